// Round 14
// baseline (1598.446 us; speedup 1.0000x reference)
//
#include <hip/hip_runtime.h>
#include <cstdint>

typedef __bf16 bf16x8 __attribute__((ext_vector_type(8)));
typedef __bf16 bf16x4 __attribute__((ext_vector_type(4)));
typedef float  f32x4  __attribute__((ext_vector_type(4)));

#define VOCAB 32000
#define EMB   512
#define HID   1024
#define LAT   512
#define BATCH 32
#define TSTEP 127          // T-1
#define MROWS 4064         // TSTEP*BATCH
#define MPAD  4096
#define G4    4096         // 4*HID
#define NBLK  128          // lstm worker blocks
#define NTM   32           // logits M tiles (128-tile fallback)
#define NTN   250          // logits N tiles (128-tile fallback)
#define FSTRIDE 64         // flag spacing in u32 (256 B apart, line-exclusive)

__device__ __forceinline__ float sigf(float x){ return 1.0f / (1.0f + __expf(-x)); }
__device__ __forceinline__ float tanhfast(float x){
    float ax = fabsf(x);
    float e  = __expf(-2.0f * ax);
    float t  = (1.0f - e) / (1.0f + e);
    return copysignf(t, x);
}

// async global->LDS, 16B/lane; LDS base wave-uniform (HW adds lane*16)
__device__ __forceinline__ void gll16(void* lds, const void* gsrc){
    __builtin_amdgcn_global_load_lds(
        (const __attribute__((address_space(1))) unsigned int*)gsrc,
        (__attribute__((address_space(3))) unsigned int*)lds,
        16, 0, 0);
}
// raw workgroup barrier WITH compiler memory fence (no vmcnt drain)
__device__ __forceinline__ void bar(){ asm volatile("s_barrier" ::: "memory"); }

// ---------------------------------------------------------------------------
// K0 (grid 192): blocks 0..127: h0 = latent@W_lh^T + b_lh -> hbuf[0]; zero
// Hall pad rows; zero scattered flags + done. blocks 128..191: W_hh cvt.
// ---------------------------------------------------------------------------
__global__ __launch_bounds__(256) void init_kernel(
    const float* __restrict__ latent,
    const float* __restrict__ Wlh,
    const float* __restrict__ blh,
    __bf16* __restrict__ h0,
    __bf16* __restrict__ Hall,
    unsigned* __restrict__ flags,
    const float* __restrict__ Whh,
    __bf16* __restrict__ Whhb)
{
    if (blockIdx.x >= 128){
        const int n4 = G4 * HID / 4;
        for (int i = (blockIdx.x - 128) * 256 + threadIdx.x; i < n4; i += 64 * 256){
            float4 v = ((const float4*)Whh)[i];
            bf16x4 o = { (__bf16)v.x, (__bf16)v.y, (__bf16)v.z, (__bf16)v.w };
            ((bf16x4*)Whhb)[i] = o;
        }
        return;
    }
    if (blockIdx.x == 0 && threadIdx.x <= NBLK)
        flags[threadIdx.x * FSTRIDE] = 0u;     // 128 flags + done (slot 128)

    int id = blockIdx.x * 256 + threadIdx.x;   // 32768 = BATCH*HID
    int b = id >> 10, j = id & 1023;
    float s = blh[j];
    const float4* lr = (const float4*)(latent + (size_t)b * LAT);
    const float4* wr = (const float4*)(Wlh + (size_t)j * LAT);
    for (int k = 0; k < LAT / 4; ++k){
        float4 a = lr[k], w = wr[k];
        s += a.x * w.x + a.y * w.y + a.z * w.z + a.w * w.w;
    }
    h0[id] = (__bf16)s;                         // hbuf[0][b][j]
    Hall[(size_t)MROWS * HID + id] = (__bf16)0.0f;  // pad rows 4064..4095
}

// ---------------------------------------------------------------------------
// K1 (grid 32 x 40): y<32: xg = emb[tok]@W_ih^T + b_ih + b_hh.
// y>=32 (256 blocks): W_out fp32->bf16 (boundary-flushed before mega2).
// ---------------------------------------------------------------------------
__global__ __launch_bounds__(256) void gemm_xg(
    const float* __restrict__ emb,
    const float* __restrict__ Wih,
    const int*   __restrict__ tok,
    float*       __restrict__ xg,
    const float* __restrict__ bih,
    const float* __restrict__ bhh,
    const float* __restrict__ Woutf,
    __bf16*      __restrict__ Woutb)
{
    if (blockIdx.y >= MPAD / 128){
        if (Woutb){
            const int n4 = VOCAB * HID / 4;
            int cb = (blockIdx.y - 32) * 32 + blockIdx.x;   // 0..255
            for (int i = cb * 256 + threadIdx.x; i < n4; i += 256 * 256){
                float4 v = ((const float4*)Woutf)[i];
                bf16x4 o = { (__bf16)v.x, (__bf16)v.y, (__bf16)v.z, (__bf16)v.w };
                ((bf16x4*)Woutb)[i] = o;
            }
        }
        return;
    }

    __shared__ __bf16 As[2][128 * 32];
    __shared__ __bf16 Bs[2][128 * 32];

    const int tid  = threadIdx.x;
    const int wid  = tid >> 6, lane = tid & 63;
    const int tile_n = blockIdx.x, tile_m = blockIdx.y;
    const int wr = wid >> 1, wc = wid & 1;

    f32x4 acc[4][4] = {};

    auto stage = [&](int kt, int buf){
        #pragma unroll
        for (int j = 0; j < 2; ++j){
            const int slot = tid + j * 256;
            const int row  = slot >> 2;
            const int kb   = kt * 32 + (slot & 3) * 8;
            {
                const int brow = tile_n * 128 + row;
                const float4* p = (const float4*)(Wih + (size_t)brow * EMB + kb);
                float4 u = p[0], v = p[1];
                bf16x8 w = { (__bf16)u.x, (__bf16)u.y, (__bf16)u.z, (__bf16)u.w,
                             (__bf16)v.x, (__bf16)v.y, (__bf16)v.z, (__bf16)v.w };
                *(bf16x8*)&Bs[buf][row * 32 + (slot & 3) * 8] = w;
            }
            {
                int r = tile_m * 128 + row;
                int rc = (r < MROWS) ? r : (MROWS - 1);
                int token = tok[(rc & 31) * 128 + (rc >> 5)];   // tokens[b][t]
                const float4* p = (const float4*)(emb + (size_t)token * EMB + kb);
                float4 u = p[0], v = p[1];
                bf16x8 w = { (__bf16)u.x, (__bf16)u.y, (__bf16)u.z, (__bf16)u.w,
                             (__bf16)v.x, (__bf16)v.y, (__bf16)v.z, (__bf16)v.w };
                *(bf16x8*)&As[buf][row * 32 + (slot & 3) * 8] = w;
            }
        }
    };

    const int KT = EMB / 32;
    stage(0, 0);
    for (int kt = 0; kt < KT; ++kt){
        const int buf = kt & 1;
        __syncthreads();
        if (kt + 1 < KT) stage(kt + 1, buf ^ 1);
        const __bf16* Abuf = As[buf];
        const __bf16* Bbuf = Bs[buf];
        const int ar = lane & 15, ko = (lane >> 4) * 8;
        bf16x8 av[4], bv[4];
        #pragma unroll
        for (int m = 0; m < 4; ++m)
            av[m] = *(const bf16x8*)&Abuf[(wr * 64 + m * 16 + ar) * 32 + ko];
        #pragma unroll
        for (int n = 0; n < 4; ++n)
            bv[n] = *(const bf16x8*)&Bbuf[(wc * 64 + n * 16 + ar) * 32 + ko];
        #pragma unroll
        for (int m = 0; m < 4; ++m)
            #pragma unroll
            for (int n = 0; n < 4; ++n)
                acc[m][n] = __builtin_amdgcn_mfma_f32_16x16x32_bf16(av[m], bv[n], acc[m][n], 0, 0, 0);
    }

    const int r0 = tile_m * 128 + wr * 64 + ((lane >> 4) << 2);
    const int c0 = tile_n * 128 + wc * 64 + (lane & 15);
    #pragma unroll
    for (int m = 0; m < 4; ++m){
        #pragma unroll
        for (int n = 0; n < 4; ++n){
            const int col = c0 + n * 16;
            float badd = bih[col] + bhh[col];
            #pragma unroll
            for (int q = 0; q < 4; ++q){
                int row = r0 + m * 16 + q;
                xg[(size_t)row * G4 + col] = acc[m][n][q] + badd;
            }
        }
    }
}

// ---------------------------------------------------------------------------
// MEGA2: cooperative, 256 blocks x 512 thr, 128KB LDS -> HW-forced 1 block/CU
// -> blocks get DEDICATED CUs (no lstm/gemm sharing, unlike R9).
//   blocks 0..127   : LSTM (tids 0..255 active; 256..511 barrier-only).
//                     Block 0 publishes done=t+1 after its flag poll.
//   blocks 128..255 : logits GEMM, 256^2 tile, BK=32, ring-4 LDS, counted
//                     vmcnt. Block gid has FIXED tm = gid&15 (128%16==0) ->
//                     ONE done-wait, then streams its 15-16 tiles.
// ---------------------------------------------------------------------------
__global__ __launch_bounds__(512) void mega2(
    const float*  __restrict__ xg,
    __bf16*       __restrict__ Hall,
    __bf16*       __restrict__ hbuf,
    const __bf16* __restrict__ Whhb,
    unsigned*     __restrict__ flags,     // 128 scattered flags; done at slot 128
    const __bf16* __restrict__ Woutb,
    float*        __restrict__ C,
    const float*  __restrict__ bout)
{
    __shared__ __align__(16) char smem[131072];
    unsigned* done = flags + NBLK * FSTRIDE;

    const int tid = threadIdx.x, wid = tid >> 6, lane = tid & 63;

    if (blockIdx.x < NBLK){
        // ======================= LSTM role =======================
        float* lds_g = (float*)smem;               // 16KB of the 128KB
        const int jb = blockIdx.x * 8;

        bf16x8 bfrag[2][8];
        if (tid < 256){
            const int gl = lane & 15, ko = (lane >> 4) * 8;
            #pragma unroll
            for (int nt = 0; nt < 2; ++nt){
                int gg = nt * 16 + gl;
                const __bf16* base =
                    Whhb + (size_t)((gg >> 3) * HID + jb + (gg & 7)) * HID + wid * 256 + ko;
                #pragma unroll
                for (int ks = 0; ks < 8; ++ks)
                    bfrag[nt][ks] = *(const bf16x8*)(base + ks * 32);
            }
        }

        const int b2 = tid >> 2, up0 = (tid & 3) * 2;
        const int mt2 = b2 >> 4, r2 = b2 & 15, reg2 = r2 & 3, lb2 = (r2 >> 2) << 4;
        float cst[2] = {0.0f, 0.0f};

        const float* xq = xg + (size_t)b2 * G4 + jb + up0;
        float2 xv[4];
        if (tid < 128){
            #pragma unroll
            for (int g = 0; g < 4; ++g) xv[g] = *(const float2*)(xq + g * HID);
        }
        const size_t e0 = (size_t)(lane & 15) * HID + wid * 256 + (lane >> 4) * 8;

        for (int t = 0; t < TSTEP; ++t){
            if (tid < 256){
                const unsigned long long* hq =
                    (const unsigned long long*)(hbuf + (size_t)(t & 1) * (BATCH * HID));
                union { unsigned long long q[2]; bf16x8 v; } xa[16];
                #pragma unroll
                for (int ks = 0; ks < 8; ++ks){
                    size_t q0 = (e0 + (size_t)ks * 32) >> 2;
                    size_t q1 = q0 + ((size_t)16 * HID >> 2);
                    xa[ks].q[0]     = __hip_atomic_load(hq + q0,     __ATOMIC_RELAXED, __HIP_MEMORY_SCOPE_AGENT);
                    xa[ks].q[1]     = __hip_atomic_load(hq + q0 + 1, __ATOMIC_RELAXED, __HIP_MEMORY_SCOPE_AGENT);
                    xa[8 + ks].q[0] = __hip_atomic_load(hq + q1,     __ATOMIC_RELAXED, __HIP_MEMORY_SCOPE_AGENT);
                    xa[8 + ks].q[1] = __hip_atomic_load(hq + q1 + 1, __ATOMIC_RELAXED, __HIP_MEMORY_SCOPE_AGENT);
                }
                f32x4 a00 = {}, a01 = {}, a10 = {}, a11 = {};
                #pragma unroll
                for (int ks = 0; ks < 8; ++ks){
                    a00 = __builtin_amdgcn_mfma_f32_16x16x32_bf16(xa[ks].v,     bfrag[0][ks], a00, 0, 0, 0);
                    a01 = __builtin_amdgcn_mfma_f32_16x16x32_bf16(xa[ks].v,     bfrag[1][ks], a01, 0, 0, 0);
                    a10 = __builtin_amdgcn_mfma_f32_16x16x32_bf16(xa[8 + ks].v, bfrag[0][ks], a10, 0, 0, 0);
                    a11 = __builtin_amdgcn_mfma_f32_16x16x32_bf16(xa[8 + ks].v, bfrag[1][ks], a11, 0, 0, 0);
                }
                #pragma unroll
                for (int q = 0; q < 4; ++q){
                    lds_g[((0 * 4 + wid) * 4 + q) * 64 + lane] = a00[q];
                    lds_g[((1 * 4 + wid) * 4 + q) * 64 + lane] = a01[q];
                    lds_g[((2 * 4 + wid) * 4 + q) * 64 + lane] = a10[q];
                    lds_g[((3 * 4 + wid) * 4 + q) * 64 + lane] = a11[q];
                }
            }
            __syncthreads();

            if (tid < 128){
                const float* xn = xq + (size_t)(t + 1) * (BATCH * G4);
                float2 xnew[4];
                #pragma unroll
                for (int g = 0; g < 4; ++g) xnew[g] = *(const float2*)(xn + g * HID);

                float h2[2];
                #pragma unroll
                for (int du = 0; du < 2; ++du){
                    int u2 = up0 + du;
                    float gate[4];
                    #pragma unroll
                    for (int ty = 0; ty < 4; ++ty){
                        int gg = ty * 8 + u2;
                        int mtnt = mt2 * 2 + (gg >> 4);
                        int li = lb2 | (gg & 15);
                        float s = 0.0f;
                        #pragma unroll
                        for (int w = 0; w < 4; ++w)
                            s += lds_g[((mtnt * 4 + w) * 4 + reg2) * 64 + li];
                        gate[ty] = s;
                    }
                    float gi = gate[0] + ((du == 0) ? xv[0].x : xv[0].y);
                    float gf = gate[1] + ((du == 0) ? xv[1].x : xv[1].y);
                    float gc = gate[2] + ((du == 0) ? xv[2].x : xv[2].y);
                    float go = gate[3] + ((du == 0) ? xv[3].x : xv[3].y);
                    float c = sigf(gf) * cst[du] + sigf(gi) * tanhfast(gc);
                    cst[du] = c;
                    h2[du] = sigf(go) * tanhfast(c);
                }
                #pragma unroll
                for (int g = 0; g < 4; ++g) xv[g] = xnew[g];

                union { __bf16 h[2]; unsigned u; } pk;
                pk.h[0] = (__bf16)h2[0]; pk.h[1] = (__bf16)h2[1];
                unsigned* hw = (unsigned*)(hbuf + (size_t)((t + 1) & 1) * (BATCH * HID)
                                           + (size_t)b2 * HID + jb + up0);
                __hip_atomic_store(hw, pk.u, __ATOMIC_RELAXED, __HIP_MEMORY_SCOPE_AGENT);
                // Hall agent-store BEFORE the drain (gemm role reads it live)
                __hip_atomic_store((unsigned*)(Hall + ((size_t)t * BATCH + b2) * HID + jb + up0),
                                   pk.u, __ATOMIC_RELAXED, __HIP_MEMORY_SCOPE_AGENT);
            }

            __syncthreads();               // vmcnt(0): agent stores COMPLETE
            if (tid == 0)
                __hip_atomic_store(&flags[blockIdx.x * FSTRIDE], (unsigned)(t + 1),
                                   __ATOMIC_RELAXED, __HIP_MEMORY_SCOPE_AGENT);
            if (wid == 0 && (t + 1 < TSTEP || blockIdx.x == 0)){
                const unsigned tgt = (unsigned)(t + 1);
                for (;;){
                    unsigned f0 = __hip_atomic_load(&flags[lane * FSTRIDE],
                                      __ATOMIC_RELAXED, __HIP_MEMORY_SCOPE_AGENT);
                    unsigned f1 = __hip_atomic_load(&flags[(lane + 64) * FSTRIDE],
                                      __ATOMIC_RELAXED, __HIP_MEMORY_SCOPE_AGENT);
                    if (f0 >= tgt && f1 >= tgt) break;
                    __builtin_amdgcn_s_sleep(1);
                }
                if (blockIdx.x == 0 && lane == 0)
                    __hip_atomic_store(done, tgt, __ATOMIC_RELAXED, __HIP_MEMORY_SCOPE_AGENT);
            }
            __syncthreads();
        }
        return;
    }

    // ======================= GEMM role =======================
    if (!Woutb) return;
    typedef __bf16 (*lds3_t)[256][32];
    lds3_t sA = (lds3_t)smem;                      // [4][256][32] = 64KB
    lds3_t sB = (lds3_t)(smem + 65536);            // [4][256][32] = 64KB

    const int gid = blockIdx.x - NBLK;             // [0,128)
    const int wm = wid >> 2, wn = wid & 3;
    const int tmF = gid & 15;                      // fixed M-tile (128%16==0)
    {
        const unsigned need = (unsigned)((8 * tmF + 8 > TSTEP) ? TSTEP : 8 * tmF + 8);
        if (tid == 0){
            while (__hip_atomic_load(done, __ATOMIC_RELAXED, __HIP_MEMORY_SCOPE_AGENT) < need)
                __builtin_amdgcn_s_sleep(16);
        }
        __syncthreads();
    }

    const int sr  = tid >> 2;                      // staging row in half [0,128)
    const int scb = tid & 3;                       // 16B chunk in row
    const int fr = lane & 15, fk = (lane >> 4) * 8;
    const int KT = HID / 32;                       // 32

    for (int i = gid; i < 2000; i += 128){
        const int tm = i & 15, tn = i >> 4;        // tm == tmF
        const __bf16* gA = Hall  + (size_t)(tm * 256 + sr) * HID + scb * 8;
        const __bf16* gB = Woutb + (size_t)(tn * 256 + sr) * HID + scb * 8;
        char* const dA0 = (char*)smem + wid * 1024;
        char* const dB0 = (char*)smem + 65536 + wid * 1024;

        auto stageA = [&](int kt){
            const int sl = kt & 3;
            gll16(dA0 + sl * 16384,        gA + (size_t)kt * 32);
            gll16(dA0 + sl * 16384 + 8192, gA + (size_t)128 * HID + (size_t)kt * 32);
        };
        auto stageB = [&](int kt){
            const int sl = kt & 3;
            gll16(dB0 + sl * 16384,        gB + (size_t)kt * 32);
            gll16(dB0 + sl * 16384 + 8192, gB + (size_t)128 * HID + (size_t)kt * 32);
        };

        f32x4 acc[8][4] = {};
        stageA(0); stageB(0); stageA(1); stageB(1); stageA(2); stageB(2);
        asm volatile("s_waitcnt vmcnt(8)" ::: "memory");
        bar();

        bf16x8 bfr[4], afr[4];
        for (int kt = 0; kt < KT; ++kt){
            const int sl = kt & 3;
            // phase 0: B(all) + A(mf0-3); stage A(kt+3)
            #pragma unroll
            for (int nf = 0; nf < 4; ++nf)
                bfr[nf] = *(const bf16x8*)&sA[0][0][0 +
                    ((size_t)0)] , bfr[nf] = *(const bf16x8*)&sB[sl][wn * 64 + nf * 16 + fr][fk];
            #pragma unroll
            for (int mf = 0; mf < 4; ++mf)
                afr[mf] = *(const bf16x8*)&sA[sl][wm * 128 + mf * 16 + fr][fk];
            if (kt + 3 < KT) stageA(kt + 3);
            bar();
            asm volatile("s_waitcnt lgkmcnt(0)" ::: "memory");
            __builtin_amdgcn_sched_barrier(0);
            __builtin_amdgcn_s_setprio(1);
            #pragma unroll
            for (int mf = 0; mf < 4; ++mf)
                #pragma unroll
                for (int nf = 0; nf < 4; ++nf)
                    acc[mf][nf] = __builtin_amdgcn_mfma_f32_16x16x32_bf16(
                        afr[mf], bfr[nf], acc[mf][nf], 0, 0, 0);
            __builtin_amdgcn_s_setprio(0);
            bar();
            // phase 1: A(mf4-7); stage B(kt+3)
            #pragma unroll
            for (int mf = 0; mf < 4; ++mf)
                afr[mf] = *(const bf16x8*)&sA[sl][wm * 128 + (mf + 4) * 16 + fr][fk];
            if (kt + 3 < KT) stageB(kt + 3);
            bar();
            asm volatile("s_waitcnt lgkmcnt(0)" ::: "memory");
            __builtin_amdgcn_sched_barrier(0);
            __builtin_amdgcn_s_setprio(1);
            #pragma unroll
            for (int mf = 0; mf < 4; ++mf)
                #pragma unroll
                for (int nf = 0; nf < 4; ++nf)
                    acc[mf + 4][nf] = __builtin_amdgcn_mfma_f32_16x16x32_bf16(
                        afr[mf], bfr[nf], acc[mf + 4][nf], 0, 0, 0);
            __builtin_amdgcn_s_setprio(0);
            if (kt < KT - 3)       asm volatile("s_waitcnt vmcnt(8)" ::: "memory");
            else if (kt == KT - 3) asm volatile("s_waitcnt vmcnt(4)" ::: "memory");
            else if (kt == KT - 2) asm volatile("s_waitcnt vmcnt(0)" ::: "memory");
            bar();
        }

        #pragma unroll
        for (int mf = 0; mf < 8; ++mf){
            #pragma unroll
            for (int nf = 0; nf < 4; ++nf){
                const int col = tn * 256 + wn * 64 + nf * 16 + fr;
                const float badd = bout[col];
                #pragma unroll
                for (int q = 0; q < 4; ++q){
                    int row = tm * 256 + wm * 128 + mf * 16 + (lane >> 4) * 4 + q;
                    if (row < MROWS){
                        int t = row >> 5, b = row & 31;
                        __builtin_nontemporal_store(acc[mf][nf][q] + badd,
                            &C[((size_t)b * TSTEP + t) * VOCAB + col]);
                    }
                }
            }
        }
        __syncthreads();    // LDS safe for next tile
    }
}

// ---------------------------------------------------------------------------
// Fallback serial path (R12-proven): lstm-only coop + 128-tile logits GEMM
// ---------------------------------------------------------------------------
__global__ __launch_bounds__(256) void lstm_coop(
    const float*  __restrict__ xg,
    __bf16*       __restrict__ Hall,
    __bf16*       __restrict__ hbuf,
    const __bf16* __restrict__ Whhb,
    unsigned*     __restrict__ flags)
{
    __shared__ float lds_g[4 * 4 * 4 * 64];
    const int tid = threadIdx.x, wid = tid >> 6, lane = tid & 63;
    const int jb = blockIdx.x * 8;

    bf16x8 bfrag[2][8];
    {
        const int gl = lane & 15, ko = (lane >> 4) * 8;
        #pragma unroll
        for (int nt = 0; nt < 2; ++nt){
            int gg = nt * 16 + gl;
            const __bf16* base =
                Whhb + (size_t)((gg >> 3) * HID + jb + (gg & 7)) * HID + wid * 256 + ko;
            #pragma unroll
            for (int ks = 0; ks < 8; ++ks)
                bfrag[nt][ks] = *(const bf16x8*)(base + ks * 32);
        }
    }

    const int b2 = tid >> 2, up0 = (tid & 3) * 2;
    const int mt2 = b2 >> 4, r2 = b2 & 15, reg2 = r2 & 3, lb2 = (r2 >> 2) << 4;
    float cst[2] = {0.0f, 0.0f};

    const float* xq = xg + (size_t)b2 * G4 + jb + up0;
    float2 xv[4];
    if (tid < 128){
        #pragma unroll
        for (int g = 0; g < 4; ++g) xv[g] = *(const float2*)(xq + g * HID);
    }
    const size_t e0 = (size_t)(lane & 15) * HID + wid * 256 + (lane >> 4) * 8;

    for (int t = 0; t < TSTEP; ++t){
        const unsigned long long* hq =
            (const unsigned long long*)(hbuf + (size_t)(t & 1) * (BATCH * HID));
        union { unsigned long long q[2]; bf16x8 v; } xa[16];
        #pragma unroll
        for (int ks = 0; ks < 8; ++ks){
            size_t q0 = (e0 + (size_t)ks * 32) >> 2;
            size_t q1 = q0 + ((size_t)16 * HID >> 2);
            xa[ks].q[0]     = __hip_atomic_load(hq + q0,     __ATOMIC_RELAXED, __HIP_MEMORY_SCOPE_AGENT);
            xa[ks].q[1]     = __hip_atomic_load(hq + q0 + 1, __ATOMIC_RELAXED, __HIP_MEMORY_SCOPE_AGENT);
            xa[8 + ks].q[0] = __hip_atomic_load(hq + q1,     __ATOMIC_RELAXED, __HIP_MEMORY_SCOPE_AGENT);
            xa[8 + ks].q[1] = __hip_atomic_load(hq + q1 + 1, __ATOMIC_RELAXED, __HIP_MEMORY_SCOPE_AGENT);
        }
        f32x4 a00 = {}, a01 = {}, a10 = {}, a11 = {};
        #pragma unroll
        for (int ks = 0; ks < 8; ++ks){
            a00 = __builtin_amdgcn_mfma_f32_16x16x32_bf16(xa[ks].v,     bfrag[0][ks], a00, 0, 0, 0);
            a01 = __builtin_amdgcn_mfma_f32_16x16x32_bf16(xa[ks].v,     bfrag[1][ks], a01, 0, 0, 0);
            a10 = __builtin_amdgcn_mfma_f32_16x16x32_bf16(xa[8 + ks].v, bfrag[0][ks], a10, 0, 0, 0);
            a11 = __builtin_amdgcn_mfma_f32_16x16x32_bf16(xa[8 + ks].v, bfrag[1][ks], a11, 0, 0, 0);
        }
        #pragma unroll
        for (int q = 0; q < 4; ++q){
            lds_g[((0 * 4 + wid) * 4 + q) * 64 + lane] = a00[q];
            lds_g[((1 * 4 + wid) * 4 + q) * 64 + lane] = a01[q];
            lds_g[((2 * 4 + wid) * 4 + q) * 64 + lane] = a10[q];
            lds_g[((3 * 4 + wid) * 4 + q) * 64 + lane] = a11[q];
        }
        __syncthreads();

        unsigned pku = 0;
        if (tid < 128){
            const float* xn = xq + (size_t)(t + 1) * (BATCH * G4);
            float2 xnew[4];
            #pragma unroll
            for (int g = 0; g < 4; ++g) xnew[g] = *(const float2*)(xn + g * HID);

            float h2[2];
            #pragma unroll
            for (int du = 0; du < 2; ++du){
                int u2 = up0 + du;
                float gate[4];
                #pragma unroll
                for (int ty = 0; ty < 4; ++ty){
                    int gg = ty * 8 + u2;
                    int mtnt = mt2 * 2 + (gg >> 4);
                    int li = lb2 | (gg & 15);
                    float s = 0.0f;
                    #pragma unroll
                    for (int w = 0; w < 4; ++w)
                        s += lds_g[((mtnt * 4 + w) * 4 + reg2) * 64 + li];
                    gate[ty] = s;
                }
                float gi = gate[0] + ((du == 0) ? xv[0].x : xv[0].y);
                float gf = gate[1] + ((du == 0) ? xv[1].x : xv[1].y);
                float gc = gate[2] + ((du == 0) ? xv[2].x : xv[2].y);
                float go = gate[3] + ((du == 0) ? xv[3].x : xv[3].y);
                float c = sigf(gf) * cst[du] + sigf(gi) * tanhfast(gc);
                cst[du] = c;
                h2[du] = sigf(go) * tanhfast(c);
            }
            #pragma unroll
            for (int g = 0; g < 4; ++g) xv[g] = xnew[g];

            union { __bf16 h[2]; unsigned u; } pk;
            pk.h[0] = (__bf16)h2[0]; pk.h[1] = (__bf16)h2[1];
            pku = pk.u;
            unsigned* hw = (unsigned*)(hbuf + (size_t)((t + 1) & 1) * (BATCH * HID)
                                       + (size_t)b2 * HID + jb + up0);
            __hip_atomic_store(hw, pku, __ATOMIC_RELAXED, __HIP_MEMORY_SCOPE_AGENT);
        }

        if (t + 1 == TSTEP){
            if (tid < 128)
                *(unsigned*)(Hall + ((size_t)t * BATCH + b2) * HID + jb + up0) = pku;
            break;
        }

        __syncthreads();
        if (tid == 0)
            __hip_atomic_store(&flags[blockIdx.x * FSTRIDE], (unsigned)(t + 1),
                               __ATOMIC_RELAXED, __HIP_MEMORY_SCOPE_AGENT);
        if (tid < 128)
            *(unsigned*)(Hall + ((size_t)t * BATCH + b2) * HID + jb + up0) = pku;
        if (wid == 0){
            const unsigned tgt = (unsigned)(t + 1);
            for (;;){
                unsigned f0 = __hip_atomic_load(&flags[lane * FSTRIDE],
                                  __ATOMIC_RELAXED, __HIP_MEMORY_SCOPE_AGENT);
                unsigned f1 = __hip_atomic_load(&flags[(lane + 64) * FSTRIDE],
                                  __ATOMIC_RELAXED, __HIP_MEMORY_SCOPE_AGENT);
                if (f0 >= tgt && f1 >= tgt) break;
                __builtin_amdgcn_s_sleep(1);
            }
        }
        __syncthreads();
    }
}

template<int BF16B>
__global__ __launch_bounds__(256) void gemm_logits(
    const __bf16* __restrict__ A,
    const float*  __restrict__ Bf,
    const __bf16* __restrict__ Bb,
    float*        __restrict__ C,
    const float*  __restrict__ bias)
{
    __shared__ __bf16 As[2][128 * 32];
    __shared__ __bf16 Bs[2][128 * 32];

    const int tid  = threadIdx.x;
    const int wid  = tid >> 6, lane = tid & 63;
    const int bid = blockIdx.x;
    const int s   = (bid & 7) * (NTM * NTN / 8) + (bid >> 3);
    const int g   = s / (8 * NTN), rem = s % (8 * NTN);
    const int tile_m = g * 8 + (rem & 7);
    const int tile_n = rem >> 3;
    const int wr = wid >> 1, wc = wid & 1;

    f32x4 acc[4][4] = {};

    auto stage = [&](int kt, int buf){
        const int kb = kt * 32 + (lane & 3) * 8;
        #pragma unroll
        for (int c2 = 0; c2 < 2; ++c2){
            int rA = tile_m * 128 + c2 * 64 + wid * 16 + (lane >> 2);
            gll16(&As[buf][c2 * 2048 + wid * 512], A + (size_t)rA * HID + kb);
            if constexpr (BF16B){
                int rB = tile_n * 128 + c2 * 64 + wid * 16 + (lane >> 2);
                gll16(&Bs[buf][c2 * 2048 + wid * 512], Bb + (size_t)rB * HID + kb);
            }
        }
        if constexpr (!BF16B){
            #pragma unroll
            for (int j = 0; j < 2; ++j){
                const int slot = tid + j * 256;
                const int row  = slot >> 2;
                const int kb2  = kt * 32 + (slot & 3) * 8;
                const int brow = tile_n * 128 + row;
                const float4* p = (const float4*)(Bf + (size_t)brow * HID + kb2);
                float4 u = p[0], v = p[1];
                bf16x8 w = { (__bf16)u.x, (__bf16)u.y, (__bf16)u.z, (__bf16)u.w,
                             (__bf16)v.x, (__bf16)v.y, (__bf16)v.z, (__bf16)v.w };
                *(bf16x8*)&Bs[buf][row * 32 + (slot & 3) * 8] = w;
            }
        }
    };

    const int KT = HID / 32;
    stage(0, 0);
    for (int kt = 0; kt < KT; ++kt){
        const int buf = kt & 1;
        __syncthreads();
        if (kt + 1 < KT) stage(kt + 1, buf ^ 1);
        const __bf16* Abuf = As[buf];
        const __bf16* Bbuf = Bs[buf];
        const int ar = lane & 15, ko = (lane >> 4) * 8;
        bf16x8 av[4], bv[4];
        #pragma unroll
        for (int m = 0; m < 4; ++m)
            av[m] = *(const bf16x8*)&Abuf[(wr * 64 + m * 16 + ar) * 32 + ko];
        #pragma unroll
        for (int n = 0; n < 4; ++n)
            bv[n] = *(const bf16x8*)&Bbuf[(wc * 64 + n * 16 + ar) * 32 + ko];
        #pragma unroll
        for (int m = 0; m < 4; ++m)
            #pragma unroll
            for (int n = 0; n < 4; ++n)
                acc[m][n] = __builtin_amdgcn_mfma_f32_16x16x32_bf16(av[m], bv[n], acc[m][n], 0, 0, 0);
    }

    const int r0 = tile_m * 128 + wr * 64 + ((lane >> 4) << 2);
    const int c0 = tile_n * 128 + wc * 64 + (lane & 15);
    #pragma unroll
    for (int m = 0; m < 4; ++m){
        #pragma unroll
        for (int n = 0; n < 4; ++n){
            const int col = c0 + n * 16;
            float badd = bias[col];
            #pragma unroll
            for (int q = 0; q < 4; ++q){
                int row = r0 + m * 16 + q;
                if (row < MROWS){
                    int t = row >> 5, b = row & 31;
                    __builtin_nontemporal_store(acc[m][n][q] + badd,
                        &C[((size_t)b * TSTEP + t) * VOCAB + col]);
                }
            }
        }
    }
}

// ---------------------------------------------------------------------------
extern "C" void kernel_launch(void* const* d_in, const int* in_sizes, int n_in,
                              void* d_out, int out_size, void* d_ws, size_t ws_size,
                              hipStream_t stream)
{
    const float* latent = (const float*)d_in[0];
    const int*   tokens = (const int*)d_in[1];
    const float* emb    = (const float*)d_in[2];
    const float* Wlh    = (const float*)d_in[3];
    const float* blh    = (const float*)d_in[4];
    const float* Wih    = (const float*)d_in[5];
    const float* bih    = (const float*)d_in[6];
    const float* Whh    = (const float*)d_in[7];
    const float* bhh    = (const float*)d_in[8];
    const float* Wout   = (const float*)d_in[9];
    const float* bout   = (const float*)d_in[10];
    float* out = (float*)d_out;

    const size_t xg_b   = (size_t)MPAD * G4 * 4;        // 64 MiB
    const size_t hall_b = (size_t)MPAD * HID * 2;       // 8 MiB
    const size_t whh_b  = (size_t)G4 * HID * 2;         // 8 MiB
    const size_t wout_b = (size_t)VOCAB * HID * 2;      // 62.5 MiB
    const size_t hb_b   = (size_t)2 * BATCH * HID * 2;  // 128 KiB
    const size_t cnt_b  = (size_t)(NBLK + 1) * FSTRIDE * 4;

    char* p = (char*)d_ws;
    const bool wsA = ws_size >= xg_b + hall_b + whh_b + wout_b + hb_b + cnt_b;
    const bool wsB = ws_size >= hall_b + whh_b + wout_b + hb_b + cnt_b;

    float* xg;
    if (wsA){ xg = (float*)p; p += xg_b; }
    else    { xg = (float*)d_out; }
    __bf16* Hall = (__bf16*)p; p += hall_b;
    __bf16* Whhb = (__bf16*)p; p += whh_b;
    __bf16* Woutb = nullptr;
    if (wsA || wsB){ Woutb = (__bf16*)p; p += wout_b; }
    __bf16* hbuf = (__bf16*)p; p += hb_b;
    unsigned* flags = (unsigned*)p; p += cnt_b;

    init_kernel<<<dim3(192), dim3(256), 0, stream>>>(
        latent, Wlh, blh, hbuf, Hall, flags, Whh, Whhb);

    gemm_xg<<<dim3(G4 / 128, MPAD / 128 + 8), dim3(256), 0, stream>>>(
        emb, Wih, tokens, xg, bih, bhh, Wout, Woutb);

    bool overlapped = false;
    if (wsA && Woutb){
        const float*  xgc   = xg;
        __bf16*       hallp = Hall;
        __bf16*       hbp   = hbuf;
        const __bf16* whhp  = Whhb;
        unsigned*     flagp = flags;
        const __bf16* wob   = Woutb;
        float*        outp  = out;
        const float*  boutp = bout;
        void* args[] = { (void*)&xgc, (void*)&hallp, (void*)&hbp, (void*)&whhp,
                         (void*)&flagp, (void*)&wob, (void*)&outp, (void*)&boutp };
        hipError_t e = hipLaunchCooperativeKernel((void*)mega2, dim3(2 * NBLK),
                                                  dim3(512), args, 0, stream);
        overlapped = (e == hipSuccess);
    }

    if (!overlapped){
        {
            const float*  xgc   = xg;
            __bf16*       hallp = Hall;
            __bf16*       hbp   = hbuf;
            const __bf16* whhp  = Whhb;
            unsigned*     flagp = flags;
            void* args[] = { (void*)&xgc, (void*)&hallp, (void*)&hbp,
                             (void*)&whhp, (void*)&flagp };
            hipLaunchCooperativeKernel((void*)lstm_coop, dim3(NBLK), dim3(256),
                                       args, 0, stream);
        }
        if (Woutb)
            gemm_logits<1><<<dim3(NTM * NTN), dim3(256), 0, stream>>>(
                Hall, (const float*)nullptr, Woutb, out, bout);
        else
            gemm_logits<0><<<dim3(NTM * NTN), dim3(256), 0, stream>>>(
                Hall, Wout, (const __bf16*)nullptr, out, bout);
    }
}

// Round 15
// 1223.233 us; speedup vs baseline: 1.3067x; 1.3067x over previous
//
#include <hip/hip_runtime.h>
#include <cstdint>

typedef __bf16 bf16x8 __attribute__((ext_vector_type(8)));
typedef __bf16 bf16x4 __attribute__((ext_vector_type(4)));
typedef float  f32x4  __attribute__((ext_vector_type(4)));

#define VOCAB 32000
#define EMB   512
#define HID   1024
#define LAT   512
#define BATCH 32
#define TSTEP 127          // T-1
#define MROWS 4064         // TSTEP*BATCH
#define MPAD  4096
#define G4    4096         // 4*HID
#define NBLK  128          // lstm worker blocks
#define NTM   32           // logits M tiles (128-tile fallback)
#define NTN   250          // logits N tiles (128-tile fallback)
#define FSTRIDE 64         // flag spacing in u32 (256 B apart, line-exclusive)

__device__ __forceinline__ float sigf(float x){ return 1.0f / (1.0f + __expf(-x)); }
__device__ __forceinline__ float tanhfast(float x){
    float ax = fabsf(x);
    float e  = __expf(-2.0f * ax);
    float t  = (1.0f - e) / (1.0f + e);
    return copysignf(t, x);
}

// async global->LDS, 16B/lane; LDS base wave-uniform (HW adds lane*16)
__device__ __forceinline__ void gll16(void* lds, const void* gsrc){
    __builtin_amdgcn_global_load_lds(
        (const __attribute__((address_space(1))) unsigned int*)gsrc,
        (__attribute__((address_space(3))) unsigned int*)lds,
        16, 0, 0);
}
// raw workgroup barrier WITH compiler memory fence (no vmcnt drain)
__device__ __forceinline__ void bar(){ asm volatile("s_barrier" ::: "memory"); }

// ---------------------------------------------------------------------------
// K0 (grid 192): blocks 0..127: h0 = latent@W_lh^T + b_lh -> hbuf[0]; zero
// Hall pad rows; zero scattered flags. blocks 128..191: W_hh fp32->bf16.
// ---------------------------------------------------------------------------
__global__ __launch_bounds__(256) void init_kernel(
    const float* __restrict__ latent,
    const float* __restrict__ Wlh,
    const float* __restrict__ blh,
    __bf16* __restrict__ h0,
    __bf16* __restrict__ Hall,
    unsigned* __restrict__ flags,
    const float* __restrict__ Whh,
    __bf16* __restrict__ Whhb)
{
    if (blockIdx.x >= 128){
        const int n4 = G4 * HID / 4;
        for (int i = (blockIdx.x - 128) * 256 + threadIdx.x; i < n4; i += 64 * 256){
            float4 v = ((const float4*)Whh)[i];
            bf16x4 o = { (__bf16)v.x, (__bf16)v.y, (__bf16)v.z, (__bf16)v.w };
            ((bf16x4*)Whhb)[i] = o;
        }
        return;
    }
    if (blockIdx.x == 0 && threadIdx.x < NBLK)
        flags[threadIdx.x * FSTRIDE] = 0u;     // one flag per 256B line

    int id = blockIdx.x * 256 + threadIdx.x;   // 32768 = BATCH*HID
    int b = id >> 10, j = id & 1023;
    float s = blh[j];
    const float4* lr = (const float4*)(latent + (size_t)b * LAT);
    const float4* wr = (const float4*)(Wlh + (size_t)j * LAT);
    for (int k = 0; k < LAT / 4; ++k){
        float4 a = lr[k], w = wr[k];
        s += a.x * w.x + a.y * w.y + a.z * w.z + a.w * w.w;
    }
    h0[id] = (__bf16)s;                         // hbuf[0][b][j]
    Hall[(size_t)MROWS * HID + id] = (__bf16)0.0f;  // pad rows 4064..4095
}

// ---------------------------------------------------------------------------
// K1: xg[r][4096] = emb[tok(r)] @ W_ih^T + b_ih + b_hh   (fp32 in, fp32 out)
// ---------------------------------------------------------------------------
__global__ __launch_bounds__(256) void gemm_xg(
    const float* __restrict__ emb,
    const float* __restrict__ Wih,
    const int*   __restrict__ tok,
    float*       __restrict__ xg,
    const float* __restrict__ bih,
    const float* __restrict__ bhh)
{
    __shared__ __bf16 As[2][128 * 32];
    __shared__ __bf16 Bs[2][128 * 32];

    const int tid  = threadIdx.x;
    const int wid  = tid >> 6, lane = tid & 63;
    const int tile_n = blockIdx.x, tile_m = blockIdx.y;
    const int wr = wid >> 1, wc = wid & 1;

    f32x4 acc[4][4] = {};

    auto stage = [&](int kt, int buf){
        #pragma unroll
        for (int j = 0; j < 2; ++j){
            const int slot = tid + j * 256;
            const int row  = slot >> 2;
            const int kb   = kt * 32 + (slot & 3) * 8;
            {
                const int brow = tile_n * 128 + row;
                const float4* p = (const float4*)(Wih + (size_t)brow * EMB + kb);
                float4 u = p[0], v = p[1];
                bf16x8 w = { (__bf16)u.x, (__bf16)u.y, (__bf16)u.z, (__bf16)u.w,
                             (__bf16)v.x, (__bf16)v.y, (__bf16)v.z, (__bf16)v.w };
                *(bf16x8*)&Bs[buf][row * 32 + (slot & 3) * 8] = w;
            }
            {
                int r = tile_m * 128 + row;
                int rc = (r < MROWS) ? r : (MROWS - 1);
                int token = tok[(rc & 31) * 128 + (rc >> 5)];   // tokens[b][t]
                const float4* p = (const float4*)(emb + (size_t)token * EMB + kb);
                float4 u = p[0], v = p[1];
                bf16x8 w = { (__bf16)u.x, (__bf16)u.y, (__bf16)u.z, (__bf16)u.w,
                             (__bf16)v.x, (__bf16)v.y, (__bf16)v.z, (__bf16)v.w };
                *(bf16x8*)&As[buf][row * 32 + (slot & 3) * 8] = w;
            }
        }
    };

    const int KT = EMB / 32;
    stage(0, 0);
    for (int kt = 0; kt < KT; ++kt){
        const int buf = kt & 1;
        __syncthreads();
        if (kt + 1 < KT) stage(kt + 1, buf ^ 1);
        const __bf16* Abuf = As[buf];
        const __bf16* Bbuf = Bs[buf];
        const int ar = lane & 15, ko = (lane >> 4) * 8;
        bf16x8 av[4], bv[4];
        #pragma unroll
        for (int m = 0; m < 4; ++m)
            av[m] = *(const bf16x8*)&Abuf[(wr * 64 + m * 16 + ar) * 32 + ko];
        #pragma unroll
        for (int n = 0; n < 4; ++n)
            bv[n] = *(const bf16x8*)&Bbuf[(wc * 64 + n * 16 + ar) * 32 + ko];
        #pragma unroll
        for (int m = 0; m < 4; ++m)
            #pragma unroll
            for (int n = 0; n < 4; ++n)
                acc[m][n] = __builtin_amdgcn_mfma_f32_16x16x32_bf16(av[m], bv[n], acc[m][n], 0, 0, 0);
    }

    const int r0 = tile_m * 128 + wr * 64 + ((lane >> 4) << 2);
    const int c0 = tile_n * 128 + wc * 64 + (lane & 15);
    #pragma unroll
    for (int m = 0; m < 4; ++m){
        #pragma unroll
        for (int n = 0; n < 4; ++n){
            const int col = c0 + n * 16;
            float badd = bih[col] + bhh[col];
            #pragma unroll
            for (int q = 0; q < 4; ++q){
                int row = r0 + m * 16 + q;
                xg[(size_t)row * G4 + col] = acc[m][n][q] + badd;
            }
        }
    }
}

// ---------------------------------------------------------------------------
// K3 (new): 256^2-tile ring-4 counted-vmcnt logits GEMM WITH T2 XOR-swizzle.
// LDS [4][256][32] bf16 (64B rows). Swizzle (involution, 16B-granular):
//   byte-col ^= ((row>>2)&1)<<4 ^ ((row>>3)&1)<<5
// applied to the GLOBAL source of global_load_lds (LDS dest stays linear,
// rule #21) and to every ds_read address -> 2-way bank conflict (free).
// Structure identical to the R14-HW-verified ring kernel (serial, no gating).
// ---------------------------------------------------------------------------
__global__ __launch_bounds__(512) void gemm_logits8(
    const __bf16* __restrict__ A,     // Hall [MPAD][HID]
    const __bf16* __restrict__ B,     // W_out bf16 [VOCAB][HID]
    float*        __restrict__ C,
    const float*  __restrict__ bias)
{
    __shared__ __bf16 sA[4][256][32];   // 64 KB ring (A)
    __shared__ __bf16 sB[4][256][32];   // 64 KB ring (B)

    const int tid = threadIdx.x;
    const int wid = tid >> 6, lane = tid & 63;
    const int wm = wid >> 2, wn = wid & 3;

    // XCD swizzle (2000 % 8 == 0) + GROUP_M=4 super-tiles (bijective)
    const int bid = blockIdx.x;
    const int s   = (bid & 7) * 250 + (bid >> 3);
    const int g   = s / 500, rem = s % 500;
    const int tm  = g * 4 + (rem & 3);     // [0,16)
    const int tn  = rem >> 2;              // [0,125)

    // staging: row sr in half [0,128), 16B chunk scb; SOURCE col pre-swizzled
    const int sr  = tid >> 2;
    const int scb = tid & 3;
    const int csw = (scb * 16) ^ (((sr >> 2) & 1) << 4) ^ (((sr >> 3) & 1) << 5);
    const __bf16* gA = A + (size_t)(tm * 256 + sr) * HID + (csw >> 1);
    const __bf16* gB = B + (size_t)(tn * 256 + sr) * HID + (csw >> 1);
    char* const dA0 = (char*)&sA[0][0][0] + wid * 1024;   // + slot*16384 (+8192 half1)
    char* const dB0 = (char*)&sB[0][0][0] + wid * 1024;

    auto stageA = [&](int kt){
        const int sl = kt & 3;
        gll16(dA0 + sl * 16384,        gA + (size_t)kt * 32);
        gll16(dA0 + sl * 16384 + 8192, gA + (size_t)128 * HID + (size_t)kt * 32);
    };
    auto stageB = [&](int kt){
        const int sl = kt & 3;
        gll16(dB0 + sl * 16384,        gB + (size_t)kt * 32);
        gll16(dB0 + sl * 16384 + 8192, gB + (size_t)128 * HID + (size_t)kt * 32);
    };

    f32x4 acc[8][4] = {};
    const int fr  = lane & 15;
    // ds_read byte-col with the same swizzle (fragment rows are 16-aligned ->
    // row bits 2,3 == fr bits 2,3)
    const int fkb = ((lane >> 4) * 16) ^ (((fr >> 2) & 1) << 4) ^ (((fr >> 3) & 1) << 5);

    // prologue: 3 K-tiles in flight (12 loads); wait oldest 4 (kt0) only
    stageA(0); stageB(0); stageA(1); stageB(1); stageA(2); stageB(2);
    asm volatile("s_waitcnt vmcnt(8)" ::: "memory");
    bar();

    const int KT = HID / 32;   // 32
    bf16x8 bfr[4], afr[4];
    for (int kt = 0; kt < KT; ++kt){
        const int sl = kt & 3;
        // ---------- phase 0: B(all) + A(mf0-3); stage A(kt+3) ----------
        #pragma unroll
        for (int nf = 0; nf < 4; ++nf)
            bfr[nf] = *(const bf16x8*)((const char*)&sB[sl][wn * 64 + nf * 16 + fr][0] + fkb);
        #pragma unroll
        for (int mf = 0; mf < 4; ++mf)
            afr[mf] = *(const bf16x8*)((const char*)&sA[sl][wm * 128 + mf * 16 + fr][0] + fkb);
        if (kt + 3 < KT) stageA(kt + 3);
        bar();
        asm volatile("s_waitcnt lgkmcnt(0)" ::: "memory");
        __builtin_amdgcn_sched_barrier(0);
        __builtin_amdgcn_s_setprio(1);
        #pragma unroll
        for (int mf = 0; mf < 4; ++mf)
            #pragma unroll
            for (int nf = 0; nf < 4; ++nf)
                acc[mf][nf] = __builtin_amdgcn_mfma_f32_16x16x32_bf16(
                    afr[mf], bfr[nf], acc[mf][nf], 0, 0, 0);
        __builtin_amdgcn_s_setprio(0);
        bar();
        // ---------- phase 1: A(mf4-7); stage B(kt+3) ----------
        #pragma unroll
        for (int mf = 0; mf < 4; ++mf)
            afr[mf] = *(const bf16x8*)((const char*)&sA[sl][wm * 128 + (mf + 4) * 16 + fr][0] + fkb);
        if (kt + 3 < KT) stageB(kt + 3);
        bar();
        asm volatile("s_waitcnt lgkmcnt(0)" ::: "memory");
        __builtin_amdgcn_sched_barrier(0);
        __builtin_amdgcn_s_setprio(1);
        #pragma unroll
        for (int mf = 0; mf < 4; ++mf)
            #pragma unroll
            for (int nf = 0; nf < 4; ++nf)
                acc[mf + 4][nf] = __builtin_amdgcn_mfma_f32_16x16x32_bf16(
                    afr[mf], bfr[nf], acc[mf + 4][nf], 0, 0, 0);
        __builtin_amdgcn_s_setprio(0);
        // K-tile boundary: kt+1's 4 loads landed; kt+2/kt+3 stay in flight
        if (kt < KT - 3)       asm volatile("s_waitcnt vmcnt(8)" ::: "memory");
        else if (kt == KT - 3) asm volatile("s_waitcnt vmcnt(4)" ::: "memory");
        else if (kt == KT - 2) asm volatile("s_waitcnt vmcnt(0)" ::: "memory");
        bar();
    }

    // epilogue: scatter fp32 logits to out[b][t][v] with bias
    #pragma unroll
    for (int mf = 0; mf < 8; ++mf){
        #pragma unroll
        for (int nf = 0; nf < 4; ++nf){
            const int col = tn * 256 + wn * 64 + nf * 16 + fr;
            const float badd = bias[col];
            #pragma unroll
            for (int q = 0; q < 4; ++q){
                int row = tm * 256 + wm * 128 + mf * 16 + (lane >> 4) * 4 + q;
                if (row < MROWS){
                    int t = row >> 5, b = row & 31;
                    __builtin_nontemporal_store(acc[mf][nf][q] + badd,
                        &C[((size_t)b * TSTEP + t) * VOCAB + col]);
                }
            }
        }
    }
}

// ---------------------------------------------------------------------------
// Fallback logits GEMM (128-tile; used when Woutb missing or gemm8 rejected)
// ---------------------------------------------------------------------------
template<int BF16B>
__global__ __launch_bounds__(256) void gemm_logits(
    const __bf16* __restrict__ A,
    const float*  __restrict__ Bf,
    const __bf16* __restrict__ Bb,
    float*        __restrict__ C,
    const float*  __restrict__ bias)
{
    __shared__ __bf16 As[2][128 * 32];
    __shared__ __bf16 Bs[2][128 * 32];

    const int tid  = threadIdx.x;
    const int wid  = tid >> 6, lane = tid & 63;
    const int bid = blockIdx.x;
    const int s   = (bid & 7) * (NTM * NTN / 8) + (bid >> 3);
    const int g   = s / (8 * NTN), rem = s % (8 * NTN);
    const int tile_m = g * 8 + (rem & 7);
    const int tile_n = rem >> 3;
    const int wr = wid >> 1, wc = wid & 1;

    f32x4 acc[4][4] = {};

    auto stage = [&](int kt, int buf){
        const int kb = kt * 32 + (lane & 3) * 8;
        #pragma unroll
        for (int c2 = 0; c2 < 2; ++c2){
            int rA = tile_m * 128 + c2 * 64 + wid * 16 + (lane >> 2);
            gll16(&As[buf][c2 * 2048 + wid * 512], A + (size_t)rA * HID + kb);
            if constexpr (BF16B){
                int rB = tile_n * 128 + c2 * 64 + wid * 16 + (lane >> 2);
                gll16(&Bs[buf][c2 * 2048 + wid * 512], Bb + (size_t)rB * HID + kb);
            }
        }
        if constexpr (!BF16B){
            #pragma unroll
            for (int j = 0; j < 2; ++j){
                const int slot = tid + j * 256;
                const int row  = slot >> 2;
                const int kb2  = kt * 32 + (slot & 3) * 8;
                const int brow = tile_n * 128 + row;
                const float4* p = (const float4*)(Bf + (size_t)brow * HID + kb2);
                float4 u = p[0], v = p[1];
                bf16x8 w = { (__bf16)u.x, (__bf16)u.y, (__bf16)u.z, (__bf16)u.w,
                             (__bf16)v.x, (__bf16)v.y, (__bf16)v.z, (__bf16)v.w };
                *(bf16x8*)&Bs[buf][row * 32 + (slot & 3) * 8] = w;
            }
        }
    };

    const int KT = HID / 32;
    stage(0, 0);
    for (int kt = 0; kt < KT; ++kt){
        const int buf = kt & 1;
        __syncthreads();
        if (kt + 1 < KT) stage(kt + 1, buf ^ 1);
        const __bf16* Abuf = As[buf];
        const __bf16* Bbuf = Bs[buf];
        const int ar = lane & 15, ko = (lane >> 4) * 8;
        bf16x8 av[4], bv[4];
        #pragma unroll
        for (int m = 0; m < 4; ++m)
            av[m] = *(const bf16x8*)&Abuf[(wr * 64 + m * 16 + ar) * 32 + ko];
        #pragma unroll
        for (int n = 0; n < 4; ++n)
            bv[n] = *(const bf16x8*)&Bbuf[(wc * 64 + n * 16 + ar) * 32 + ko];
        #pragma unroll
        for (int m = 0; m < 4; ++m)
            #pragma unroll
            for (int n = 0; n < 4; ++n)
                acc[m][n] = __builtin_amdgcn_mfma_f32_16x16x32_bf16(av[m], bv[n], acc[m][n], 0, 0, 0);
    }

    const int r0 = tile_m * 128 + wr * 64 + ((lane >> 4) << 2);
    const int c0 = tile_n * 128 + wc * 64 + (lane & 15);
    #pragma unroll
    for (int m = 0; m < 4; ++m){
        #pragma unroll
        for (int n = 0; n < 4; ++n){
            const int col = c0 + n * 16;
            float badd = bias[col];
            #pragma unroll
            for (int q = 0; q < 4; ++q){
                int row = r0 + m * 16 + q;
                if (row < MROWS){
                    int t = row >> 5, b = row & 31;
                    __builtin_nontemporal_store(acc[m][n][q] + badd,
                        &C[((size_t)b * TSTEP + t) * VOCAB + col]);
                }
            }
        }
    }
}

// ---------------------------------------------------------------------------
// K2: 127 LSTM steps, ONE cooperative kernel (256 blocks). R12-proven 743us:
//   blocks 0..127   : LSTM (hot hbuf ping-pong agent atomics; scattered
//                     line-exclusive flags; deferred Hall store).
//   blocks 128..255 : W_out fp32->bf16 under the lstm shadow, then exit.
// ---------------------------------------------------------------------------
__global__ __launch_bounds__(256) void lstm_coop(
    const float*  __restrict__ xg,
    __bf16*       __restrict__ Hall,
    __bf16*       __restrict__ hbuf,    // 2 * BATCH*HID ping-pong, [0]=h0
    const __bf16* __restrict__ Whhb,
    unsigned*     __restrict__ flags,   // 128 flags, 256B apart
    const float*  __restrict__ Woutf,
    __bf16*       __restrict__ Woutb)
{
    if (blockIdx.x >= NBLK){
        if (Woutb){
            const int n4 = VOCAB * HID / 4;          // 8.192M float4
            for (int i = (blockIdx.x - NBLK) * 256 + threadIdx.x; i < n4; i += NBLK * 256){
                float4 v = ((const float4*)Woutf)[i];
                bf16x4 o = { (__bf16)v.x, (__bf16)v.y, (__bf16)v.z, (__bf16)v.w };
                ((bf16x4*)Woutb)[i] = o;
            }
        }
        return;
    }

    __shared__ float lds_g[4 * 4 * 4 * 64];    // [acc][wid][reg][lane] = 16KB
    const int tid = threadIdx.x, wid = tid >> 6, lane = tid & 63;
    const int jb = blockIdx.x * 8;

    bf16x8 bfrag[2][8];
    {
        const int gl = lane & 15, ko = (lane >> 4) * 8;
        #pragma unroll
        for (int nt = 0; nt < 2; ++nt){
            int gg = nt * 16 + gl;                     // type=gg>>3, unit=gg&7
            const __bf16* base =
                Whhb + (size_t)((gg >> 3) * HID + jb + (gg & 7)) * HID + wid * 256 + ko;
            #pragma unroll
            for (int ks = 0; ks < 8; ++ks)
                bfrag[nt][ks] = *(const bf16x8*)(base + ks * 32);
        }
    }

    const int b2 = tid >> 2, up0 = (tid & 3) * 2;
    const int mt2 = b2 >> 4, r2 = b2 & 15, reg2 = r2 & 3, lb2 = (r2 >> 2) << 4;
    float cst[2] = {0.0f, 0.0f};

    const float* xq = xg + (size_t)b2 * G4 + jb + up0;
    float2 xv[4];
    if (tid < 128){
        #pragma unroll
        for (int g = 0; g < 4; ++g) xv[g] = *(const float2*)(xq + g * HID);
    }

    const size_t e0 = (size_t)(lane & 15) * HID + wid * 256 + (lane >> 4) * 8; // elems

    for (int t = 0; t < TSTEP; ++t){
        const unsigned long long* hq =
            (const unsigned long long*)(hbuf + (size_t)(t & 1) * (BATCH * HID));
        union { unsigned long long q[2]; bf16x8 v; } xa[16];
        #pragma unroll
        for (int ks = 0; ks < 8; ++ks){
            size_t q0 = (e0 + (size_t)ks * 32) >> 2;
            size_t q1 = q0 + ((size_t)16 * HID >> 2);
            xa[ks].q[0]     = __hip_atomic_load(hq + q0,     __ATOMIC_RELAXED, __HIP_MEMORY_SCOPE_AGENT);
            xa[ks].q[1]     = __hip_atomic_load(hq + q0 + 1, __ATOMIC_RELAXED, __HIP_MEMORY_SCOPE_AGENT);
            xa[8 + ks].q[0] = __hip_atomic_load(hq + q1,     __ATOMIC_RELAXED, __HIP_MEMORY_SCOPE_AGENT);
            xa[8 + ks].q[1] = __hip_atomic_load(hq + q1 + 1, __ATOMIC_RELAXED, __HIP_MEMORY_SCOPE_AGENT);
        }
        f32x4 a00 = {}, a01 = {}, a10 = {}, a11 = {};
        #pragma unroll
        for (int ks = 0; ks < 8; ++ks){
            a00 = __builtin_amdgcn_mfma_f32_16x16x32_bf16(xa[ks].v,     bfrag[0][ks], a00, 0, 0, 0);
            a01 = __builtin_amdgcn_mfma_f32_16x16x32_bf16(xa[ks].v,     bfrag[1][ks], a01, 0, 0, 0);
            a10 = __builtin_amdgcn_mfma_f32_16x16x32_bf16(xa[8 + ks].v, bfrag[0][ks], a10, 0, 0, 0);
            a11 = __builtin_amdgcn_mfma_f32_16x16x32_bf16(xa[8 + ks].v, bfrag[1][ks], a11, 0, 0, 0);
        }
        #pragma unroll
        for (int q = 0; q < 4; ++q){
            lds_g[((0 * 4 + wid) * 4 + q) * 64 + lane] = a00[q];
            lds_g[((1 * 4 + wid) * 4 + q) * 64 + lane] = a01[q];
            lds_g[((2 * 4 + wid) * 4 + q) * 64 + lane] = a10[q];
            lds_g[((3 * 4 + wid) * 4 + q) * 64 + lane] = a11[q];
        }
        __syncthreads();

        unsigned pku = 0;
        if (tid < 128){
            const float* xn = xq + (size_t)(t + 1) * (BATCH * G4);
            float2 xnew[4];
            #pragma unroll
            for (int g = 0; g < 4; ++g) xnew[g] = *(const float2*)(xn + g * HID);

            float h2[2];
            #pragma unroll
            for (int du = 0; du < 2; ++du){
                int u2 = up0 + du;
                float gate[4];
                #pragma unroll
                for (int ty = 0; ty < 4; ++ty){
                    int gg = ty * 8 + u2;
                    int mtnt = mt2 * 2 + (gg >> 4);
                    int li = lb2 | (gg & 15);
                    float s = 0.0f;
                    #pragma unroll
                    for (int w = 0; w < 4; ++w)
                        s += lds_g[((mtnt * 4 + w) * 4 + reg2) * 64 + li];
                    gate[ty] = s;
                }
                float gi = gate[0] + ((du == 0) ? xv[0].x : xv[0].y);
                float gf = gate[1] + ((du == 0) ? xv[1].x : xv[1].y);
                float gc = gate[2] + ((du == 0) ? xv[2].x : xv[2].y);
                float go = gate[3] + ((du == 0) ? xv[3].x : xv[3].y);
                float c = sigf(gf) * cst[du] + sigf(gi) * tanhfast(gc);
                cst[du] = c;
                h2[du] = sigf(go) * tanhfast(c);
            }
            #pragma unroll
            for (int g = 0; g < 4; ++g) xv[g] = xnew[g];

            union { __bf16 h[2]; unsigned u; } pk;
            pk.h[0] = (__bf16)h2[0]; pk.h[1] = (__bf16)h2[1];
            pku = pk.u;
            unsigned* hw = (unsigned*)(hbuf + (size_t)((t + 1) & 1) * (BATCH * HID)
                                       + (size_t)b2 * HID + jb + up0);
            __hip_atomic_store(hw, pku, __ATOMIC_RELAXED, __HIP_MEMORY_SCOPE_AGENT);
        }

        if (t + 1 == TSTEP){
            if (tid < 128)
                *(unsigned*)(Hall + ((size_t)t * BATCH + b2) * HID + jb + up0) = pku;
            break;
        }

        __syncthreads();                 // vmcnt(0): hbuf agent store COMPLETE
        if (tid == 0)
            __hip_atomic_store(&flags[blockIdx.x * FSTRIDE], (unsigned)(t + 1),
                               __ATOMIC_RELAXED, __HIP_MEMORY_SCOPE_AGENT);
        if (tid < 128)                   // Hall store OFF the drain path
            *(unsigned*)(Hall + ((size_t)t * BATCH + b2) * HID + jb + up0) = pku;
        if (wid == 0){
            const unsigned tgt = (unsigned)(t + 1);
            for (;;){
                unsigned f0 = __hip_atomic_load(&flags[lane * FSTRIDE],
                                  __ATOMIC_RELAXED, __HIP_MEMORY_SCOPE_AGENT);
                unsigned f1 = __hip_atomic_load(&flags[(lane + 64) * FSTRIDE],
                                  __ATOMIC_RELAXED, __HIP_MEMORY_SCOPE_AGENT);
                if (f0 >= tgt && f1 >= tgt) break;
                __builtin_amdgcn_s_sleep(1);
            }
        }
        __syncthreads();
    }
}

// ---------------------------------------------------------------------------
extern "C" void kernel_launch(void* const* d_in, const int* in_sizes, int n_in,
                              void* d_out, int out_size, void* d_ws, size_t ws_size,
                              hipStream_t stream)
{
    const float* latent = (const float*)d_in[0];
    const int*   tokens = (const int*)d_in[1];
    const float* emb    = (const float*)d_in[2];
    const float* Wlh    = (const float*)d_in[3];
    const float* blh    = (const float*)d_in[4];
    const float* Wih    = (const float*)d_in[5];
    const float* bih    = (const float*)d_in[6];
    const float* Whh    = (const float*)d_in[7];
    const float* bhh    = (const float*)d_in[8];
    const float* Wout   = (const float*)d_in[9];
    const float* bout   = (const float*)d_in[10];
    float* out = (float*)d_out;

    const size_t xg_b   = (size_t)MPAD * G4 * 4;        // 64 MiB fp32 gate preacts
    const size_t hall_b = (size_t)MPAD * HID * 2;       // 8 MiB bf16
    const size_t whh_b  = (size_t)G4 * HID * 2;         // 8 MiB bf16
    const size_t wout_b = (size_t)VOCAB * HID * 2;      // 62.5 MiB bf16
    const size_t hb_b   = (size_t)2 * BATCH * HID * 2;  // 128 KiB ping-pong
    const size_t cnt_b  = (size_t)NBLK * FSTRIDE * 4;   // 32 KiB scattered flags

    char* p = (char*)d_ws;
    const bool wsA = ws_size >= xg_b + hall_b + whh_b + wout_b + hb_b + cnt_b;
    const bool wsB = ws_size >= hall_b + whh_b + wout_b + hb_b + cnt_b;

    float* xg;
    if (wsA){ xg = (float*)p; p += xg_b; }
    else    { xg = (float*)d_out; }      // 64 MiB scratch; consumed before K3 writes
    __bf16* Hall = (__bf16*)p; p += hall_b;
    __bf16* Whhb = (__bf16*)p; p += whh_b;
    __bf16* Woutb = nullptr;
    if (wsA || wsB){ Woutb = (__bf16*)p; p += wout_b; }
    __bf16* hbuf = (__bf16*)p; p += hb_b;
    unsigned* flags = (unsigned*)p; p += cnt_b;

    init_kernel<<<dim3(192), dim3(256), 0, stream>>>(
        latent, Wlh, blh, hbuf, Hall, flags, Whh, Whhb);

    gemm_xg<<<dim3(G4 / 128, MPAD / 128), dim3(256), 0, stream>>>(
        emb, Wih, tokens, xg, bih, bhh);

    {
        const float*  xgc   = xg;
        __bf16*       hallp = Hall;
        __bf16*       hbp   = hbuf;
        const __bf16* whhp  = Whhb;
        unsigned*     flagp = flags;
        const float*  wof   = Wout;
        __bf16*       wob   = Woutb;
        void* args[] = { (void*)&xgc, (void*)&hallp, (void*)&hbp, (void*)&whhp,
                         (void*)&flagp, (void*)&wof, (void*)&wob };
        hipLaunchCooperativeKernel((void*)lstm_coop, dim3(2 * NBLK), dim3(256),
                                   args, 0, stream);
    }

    if (Woutb){
        (void)hipGetLastError();         // clear any prior sticky error
        gemm_logits8<<<dim3(2000), dim3(512), 0, stream>>>(Hall, Woutb, out, bout);
        if (hipGetLastError() != hipSuccess){
            gemm_logits<1><<<dim3(NTM * NTN), dim3(256), 0, stream>>>(
                Hall, (const float*)nullptr, Woutb, out, bout);
        }
    } else {
        gemm_logits<0><<<dim3(NTM * NTN), dim3(256), 0, stream>>>(
            Hall, Wout, (const __bf16*)nullptr, out, bout);
    }
}

// Round 17
// 1210.287 us; speedup vs baseline: 1.3207x; 1.0107x over previous
//
#include <hip/hip_runtime.h>
#include <cstdint>

typedef __bf16 bf16x8 __attribute__((ext_vector_type(8)));
typedef __bf16 bf16x4 __attribute__((ext_vector_type(4)));
typedef float  f32x4  __attribute__((ext_vector_type(4)));

#define VOCAB 32000
#define EMB   512
#define HID   1024
#define LAT   512
#define BATCH 32
#define TSTEP 127          // T-1
#define MROWS 4064         // TSTEP*BATCH
#define MPAD  4096
#define G4    4096         // 4*HID
#define NBLK2 64           // lstm worker blocks (512 thr each)
#define NTM   32           // logits M tiles
#define NTN   250          // logits N tiles
#define FSTRIDE 64         // flag spacing in u32 (256 B apart, line-exclusive)

__device__ __forceinline__ float sigf(float x){ return 1.0f / (1.0f + __expf(-x)); }
__device__ __forceinline__ float tanhfast(float x){
    float ax = fabsf(x);
    float e  = __expf(-2.0f * ax);
    float t  = (1.0f - e) / (1.0f + e);
    return copysignf(t, x);
}

// async global->LDS, 16B/lane; LDS base wave-uniform (HW adds lane*16)
__device__ __forceinline__ void gll16(void* lds, const void* gsrc){
    __builtin_amdgcn_global_load_lds(
        (const __attribute__((address_space(1))) unsigned int*)gsrc,
        (__attribute__((address_space(3))) unsigned int*)lds,
        16, 0, 0);
}

// ---------------------------------------------------------------------------
// K0 (grid 192): blocks 0..127: h0 = latent@W_lh^T + b_lh -> hbuf[0]; zero
// Hall pad rows; zero scattered flags. blocks 128..191: W_hh fp32->bf16.
// ---------------------------------------------------------------------------
__global__ __launch_bounds__(256) void init_kernel(
    const float* __restrict__ latent,
    const float* __restrict__ Wlh,
    const float* __restrict__ blh,
    __bf16* __restrict__ h0,
    __bf16* __restrict__ Hall,
    unsigned* __restrict__ flags,
    const float* __restrict__ Whh,
    __bf16* __restrict__ Whhb)
{
    if (blockIdx.x >= 128){
        const int n4 = G4 * HID / 4;
        for (int i = (blockIdx.x - 128) * 256 + threadIdx.x; i < n4; i += 64 * 256){
            float4 v = ((const float4*)Whh)[i];
            bf16x4 o = { (__bf16)v.x, (__bf16)v.y, (__bf16)v.z, (__bf16)v.w };
            ((bf16x4*)Whhb)[i] = o;
        }
        return;
    }
    if (blockIdx.x == 0 && threadIdx.x < 128)
        flags[threadIdx.x * FSTRIDE] = 0u;     // one flag per 256B line

    int id = blockIdx.x * 256 + threadIdx.x;   // 32768 = BATCH*HID
    int b = id >> 10, j = id & 1023;
    float s = blh[j];
    const float4* lr = (const float4*)(latent + (size_t)b * LAT);
    const float4* wr = (const float4*)(Wlh + (size_t)j * LAT);
    for (int k = 0; k < LAT / 4; ++k){
        float4 a = lr[k], w = wr[k];
        s += a.x * w.x + a.y * w.y + a.z * w.z + a.w * w.w;
    }
    h0[id] = (__bf16)s;                         // hbuf[0][b][j]
    Hall[(size_t)MROWS * HID + id] = (__bf16)0.0f;  // pad rows 4064..4095
}

// ---------------------------------------------------------------------------
// K1: xg[r][4096] = emb[tok(r)] @ W_ih^T + b_ih + b_hh   (fp32 in, fp32 out)
// ---------------------------------------------------------------------------
__global__ __launch_bounds__(256) void gemm_xg(
    const float* __restrict__ emb,
    const float* __restrict__ Wih,
    const int*   __restrict__ tok,
    float*       __restrict__ xg,
    const float* __restrict__ bih,
    const float* __restrict__ bhh)
{
    __shared__ __bf16 As[2][128 * 32];
    __shared__ __bf16 Bs[2][128 * 32];

    const int tid  = threadIdx.x;
    const int wid  = tid >> 6, lane = tid & 63;
    const int tile_n = blockIdx.x, tile_m = blockIdx.y;
    const int wr = wid >> 1, wc = wid & 1;

    f32x4 acc[4][4] = {};

    auto stage = [&](int kt, int buf){
        #pragma unroll
        for (int j = 0; j < 2; ++j){
            const int slot = tid + j * 256;
            const int row  = slot >> 2;
            const int kb   = kt * 32 + (slot & 3) * 8;
            {
                const int brow = tile_n * 128 + row;
                const float4* p = (const float4*)(Wih + (size_t)brow * EMB + kb);
                float4 u = p[0], v = p[1];
                bf16x8 w = { (__bf16)u.x, (__bf16)u.y, (__bf16)u.z, (__bf16)u.w,
                             (__bf16)v.x, (__bf16)v.y, (__bf16)v.z, (__bf16)v.w };
                *(bf16x8*)&Bs[buf][row * 32 + (slot & 3) * 8] = w;
            }
            {
                int r = tile_m * 128 + row;
                int rc = (r < MROWS) ? r : (MROWS - 1);
                int token = tok[(rc & 31) * 128 + (rc >> 5)];   // tokens[b][t]
                const float4* p = (const float4*)(emb + (size_t)token * EMB + kb);
                float4 u = p[0], v = p[1];
                bf16x8 w = { (__bf16)u.x, (__bf16)u.y, (__bf16)u.z, (__bf16)u.w,
                             (__bf16)v.x, (__bf16)v.y, (__bf16)v.z, (__bf16)v.w };
                *(bf16x8*)&As[buf][row * 32 + (slot & 3) * 8] = w;
            }
        }
    };

    const int KT = EMB / 32;
    stage(0, 0);
    for (int kt = 0; kt < KT; ++kt){
        const int buf = kt & 1;
        __syncthreads();
        if (kt + 1 < KT) stage(kt + 1, buf ^ 1);
        const __bf16* Abuf = As[buf];
        const __bf16* Bbuf = Bs[buf];
        const int ar = lane & 15, ko = (lane >> 4) * 8;
        bf16x8 av[4], bv[4];
        #pragma unroll
        for (int m = 0; m < 4; ++m)
            av[m] = *(const bf16x8*)&Abuf[(wr * 64 + m * 16 + ar) * 32 + ko];
        #pragma unroll
        for (int n = 0; n < 4; ++n)
            bv[n] = *(const bf16x8*)&Bbuf[(wc * 64 + n * 16 + ar) * 32 + ko];
        #pragma unroll
        for (int m = 0; m < 4; ++m)
            #pragma unroll
            for (int n = 0; n < 4; ++n)
                acc[m][n] = __builtin_amdgcn_mfma_f32_16x16x32_bf16(av[m], bv[n], acc[m][n], 0, 0, 0);
    }

    const int r0 = tile_m * 128 + wr * 64 + ((lane >> 4) << 2);
    const int c0 = tile_n * 128 + wc * 64 + (lane & 15);
    #pragma unroll
    for (int m = 0; m < 4; ++m){
        #pragma unroll
        for (int n = 0; n < 4; ++n){
            const int col = c0 + n * 16;
            float badd = bih[col] + bhh[col];
            #pragma unroll
            for (int q = 0; q < 4; ++q){
                int row = r0 + m * 16 + q;
                xg[(size_t)row * G4 + col] = acc[m][n][q] + badd;
            }
        }
    }
}

// ---------------------------------------------------------------------------
// K3: logits = Hall @ W_out^T + b_out, 128^2 tile, GROUP_M=8 + XCD swizzle.
// SWAPPED MFMA operands: acc[m][n] = mfma(bv[n], av[m], .) so each lane's
// f32x4 holds 4 CONSECUTIVE output columns (first op -> (lane>>4)*4+q,
// second op -> lane&15) -> f32x4 nontemporal C-stores (4x fewer stores).
// ---------------------------------------------------------------------------
template<int BF16B>
__global__ __launch_bounds__(256) void gemm_logits(
    const __bf16* __restrict__ A,     // Hall, padded to MPAD rows, K=HID
    const float*  __restrict__ Bf,    // W_out fp32 (BF16B=0)
    const __bf16* __restrict__ Bb,    // W_out bf16 (BF16B=1)
    float*        __restrict__ C,
    const float*  __restrict__ bias)
{
    __shared__ __bf16 As[2][128 * 32];
    __shared__ __bf16 Bs[2][128 * 32];

    const int tid  = threadIdx.x;
    const int wid  = tid >> 6, lane = tid & 63;
    const int bid = blockIdx.x;
    const int s   = (bid & 7) * (NTM * NTN / 8) + (bid >> 3);
    const int g   = s / (8 * NTN), rem = s % (8 * NTN);
    const int tile_m = g * 8 + (rem & 7);
    const int tile_n = rem >> 3;
    const int wr = wid >> 1, wc = wid & 1;

    f32x4 acc[4][4] = {};

    auto stage = [&](int kt, int buf){
        const int kb = kt * 32 + (lane & 3) * 8;
        #pragma unroll
        for (int c2 = 0; c2 < 2; ++c2){
            int rA = tile_m * 128 + c2 * 64 + wid * 16 + (lane >> 2);
            gll16(&As[buf][c2 * 2048 + wid * 512], A + (size_t)rA * HID + kb);
            if constexpr (BF16B){
                int rB = tile_n * 128 + c2 * 64 + wid * 16 + (lane >> 2);
                gll16(&Bs[buf][c2 * 2048 + wid * 512], Bb + (size_t)rB * HID + kb);
            }
        }
        if constexpr (!BF16B){
            #pragma unroll
            for (int j = 0; j < 2; ++j){
                const int slot = tid + j * 256;
                const int row  = slot >> 2;
                const int kb2  = kt * 32 + (slot & 3) * 8;
                const int brow = tile_n * 128 + row;
                const float4* p = (const float4*)(Bf + (size_t)brow * HID + kb2);
                float4 u = p[0], v = p[1];
                bf16x8 w = { (__bf16)u.x, (__bf16)u.y, (__bf16)u.z, (__bf16)u.w,
                             (__bf16)v.x, (__bf16)v.y, (__bf16)v.z, (__bf16)v.w };
                *(bf16x8*)&Bs[buf][row * 32 + (slot & 3) * 8] = w;
            }
        }
    };

    const int KT = HID / 32;
    stage(0, 0);
    for (int kt = 0; kt < KT; ++kt){
        const int buf = kt & 1;
        __syncthreads();                 // drains vmcnt (gll) + lgkmcnt
        if (kt + 1 < KT) stage(kt + 1, buf ^ 1);
        const __bf16* Abuf = As[buf];
        const __bf16* Bbuf = Bs[buf];
        const int ar = lane & 15, ko = (lane >> 4) * 8;
        bf16x8 av[4], bv[4];
        #pragma unroll
        for (int m = 0; m < 4; ++m)
            av[m] = *(const bf16x8*)&Abuf[(wr * 64 + m * 16 + ar) * 32 + ko];
        #pragma unroll
        for (int n = 0; n < 4; ++n)
            bv[n] = *(const bf16x8*)&Bbuf[(wc * 64 + n * 16 + ar) * 32 + ko];
        #pragma unroll
        for (int m = 0; m < 4; ++m)
            #pragma unroll
            for (int n = 0; n < 4; ++n)
                acc[m][n] = __builtin_amdgcn_mfma_f32_16x16x32_bf16(
                    bv[n], av[m], acc[m][n], 0, 0, 0);   // SWAPPED
    }

    // epilogue: lane owns row = base + (lane&15); cols = base + (lane>>4)*4 +q
    const int r0 = tile_m * 128 + wr * 64 + (lane & 15);
    const int c0 = tile_n * 128 + wc * 64 + ((lane >> 4) << 2);
    #pragma unroll
    for (int m = 0; m < 4; ++m){
        const int row = r0 + m * 16;
        if (row < MROWS){
            const int t = row >> 5, b = row & 31;
            float* crow = &C[((size_t)b * TSTEP + t) * VOCAB];
            #pragma unroll
            for (int n = 0; n < 4; ++n){
                const int col = c0 + n * 16;
                const f32x4 bd = *(const f32x4*)&bias[col];
                f32x4 v = acc[m][n] + bd;
                __builtin_nontemporal_store(v, (f32x4*)&crow[col]);
            }
        }
    }
}

// ---------------------------------------------------------------------------
// K2: 127 LSTM steps, ONE cooperative kernel (256 blocks x 512 thr):
//   blocks 0..63   : LSTM. Block owns 16 units (64 gate cols = 4 type-
//                    fragments x 16 units). K split 8-ways across 8 waves ->
//                    block reads h ONCE (64KB): chip broadcast 4MB/step
//                    (halved vs 128-block). 64 line-exclusive flags.
//   blocks 64..255 : W_out fp32->bf16 under the lstm shadow, then exit.
// ---------------------------------------------------------------------------
__global__ __launch_bounds__(512) void lstm_coop(
    const float*  __restrict__ xg,
    __bf16*       __restrict__ Hall,
    __bf16*       __restrict__ hbuf,    // 2 * BATCH*HID ping-pong, [0]=h0
    const __bf16* __restrict__ Whhb,
    unsigned*     __restrict__ flags,   // 64 flags, 256B apart
    const float*  __restrict__ Woutf,
    __bf16*       __restrict__ Woutb)
{
    if (blockIdx.x >= NBLK2){
        if (Woutb){
            const int n4 = VOCAB * HID / 4;          // 8.192M float4
            for (int i = (blockIdx.x - NBLK2) * 512 + threadIdx.x; i < n4; i += 192 * 512){
                float4 v = ((const float4*)Woutf)[i];
                bf16x4 o = { (__bf16)v.x, (__bf16)v.y, (__bf16)v.z, (__bf16)v.w };
                ((bf16x4*)Woutb)[i] = o;
            }
        }
        return;
    }

    __shared__ float lds_g[8 * 8 * 4 * 64];    // [bh*4+cf][wave][q][lane] = 64KB
    const int tid = threadIdx.x, wid = tid >> 6, lane = tid & 63;
    const int jb = blockIdx.x * 16;            // 16 units per block

    // B-frags: 4 col-fragments (= gate types) x 4 ks; this wave's K-eighth.
    // frag row (lane&15) = unit; k = wid*128 + ks*32 + (lane>>4)*8
    bf16x8 bfrag[4][4];
    {
        const int un = lane & 15, ko = (lane >> 4) * 8;
        #pragma unroll
        for (int cf = 0; cf < 4; ++cf){
            const __bf16* base =
                Whhb + ((size_t)cf * HID + jb + un) * HID + wid * 128 + ko;
            #pragma unroll
            for (int ks = 0; ks < 4; ++ks)
                bfrag[cf][ks] = *(const bf16x8*)(base + ks * 32);
        }
    }

    // update-phase ownership: tid<256, (batch b2, 2 units up0..up0+1)
    const int b2 = tid >> 3, up0 = (tid & 7) * 2;
    const int mt2 = b2 >> 4, r2 = b2 & 15, reg2 = r2 & 3, lb2 = (r2 >> 2) << 4;
    float cst[2] = {0.0f, 0.0f};

    const float* xq = xg + (size_t)b2 * G4 + jb + up0;
    float2 xv[4];
    if (tid < 256){
        #pragma unroll
        for (int g = 0; g < 4; ++g) xv[g] = *(const float2*)(xq + g * HID);
    }

    const size_t e0 = (size_t)(lane & 15) * HID + wid * 128 + (lane >> 4) * 8; // elems

    for (int t = 0; t < TSTEP; ++t){
        // ---- batched h loads: this wave's K-eighth, both batch halves ----
        const unsigned long long* hq =
            (const unsigned long long*)(hbuf + (size_t)(t & 1) * (BATCH * HID));
        union { unsigned long long q[2]; bf16x8 v; } xa[8];
        #pragma unroll
        for (int ks = 0; ks < 4; ++ks){
            size_t q0 = (e0 + (size_t)ks * 32) >> 2;
            size_t q1 = q0 + ((size_t)16 * HID >> 2);
            xa[ks].q[0]     = __hip_atomic_load(hq + q0,     __ATOMIC_RELAXED, __HIP_MEMORY_SCOPE_AGENT);
            xa[ks].q[1]     = __hip_atomic_load(hq + q0 + 1, __ATOMIC_RELAXED, __HIP_MEMORY_SCOPE_AGENT);
            xa[4 + ks].q[0] = __hip_atomic_load(hq + q1,     __ATOMIC_RELAXED, __HIP_MEMORY_SCOPE_AGENT);
            xa[4 + ks].q[1] = __hip_atomic_load(hq + q1 + 1, __ATOMIC_RELAXED, __HIP_MEMORY_SCOPE_AGENT);
        }
        f32x4 a[2][4] = {};
        #pragma unroll
        for (int ks = 0; ks < 4; ++ks){
            #pragma unroll
            for (int cf = 0; cf < 4; ++cf){
                a[0][cf] = __builtin_amdgcn_mfma_f32_16x16x32_bf16(xa[ks].v,     bfrag[cf][ks], a[0][cf], 0, 0, 0);
                a[1][cf] = __builtin_amdgcn_mfma_f32_16x16x32_bf16(xa[4 + ks].v, bfrag[cf][ks], a[1][cf], 0, 0, 0);
            }
        }
        #pragma unroll
        for (int bh = 0; bh < 2; ++bh)
            #pragma unroll
            for (int cf = 0; cf < 4; ++cf)
                #pragma unroll
                for (int q = 0; q < 4; ++q)
                    lds_g[((((bh * 4 + cf) * 8 + wid) * 4) + q) * 64 + lane] = a[bh][cf][q];
        __syncthreads();

        // ---- update phase: 256 threads, 2 units each ----
        unsigned pku = 0;
        if (tid < 256){
            // issue next-step xg prefetch FIRST (overlaps LDS reduce + math)
            const float* xn = xq + (size_t)(t + 1) * (BATCH * G4);
            float2 xnew[4];
            #pragma unroll
            for (int g = 0; g < 4; ++g) xnew[g] = *(const float2*)(xn + g * HID);

            float h2[2];
            #pragma unroll
            for (int du = 0; du < 2; ++du){
                int u2 = up0 + du;                 // unit in [0,16)
                float gate[4];
                #pragma unroll
                for (int ty = 0; ty < 4; ++ty){
                    int li = lb2 | u2;
                    float s = 0.0f;
                    #pragma unroll
                    for (int w = 0; w < 8; ++w)
                        s += lds_g[((((mt2 * 4 + ty) * 8 + w) * 4) + reg2) * 64 + li];
                    gate[ty] = s;
                }
                float gi = gate[0] + ((du == 0) ? xv[0].x : xv[0].y);
                float gf = gate[1] + ((du == 0) ? xv[1].x : xv[1].y);
                float gc = gate[2] + ((du == 0) ? xv[2].x : xv[2].y);
                float go = gate[3] + ((du == 0) ? xv[3].x : xv[3].y);
                float c = sigf(gf) * cst[du] + sigf(gi) * tanhfast(gc);
                cst[du] = c;
                h2[du] = sigf(go) * tanhfast(c);
            }
            #pragma unroll
            for (int g = 0; g < 4; ++g) xv[g] = xnew[g];

            union { __bf16 h[2]; unsigned u; } pk;
            pk.h[0] = (__bf16)h2[0]; pk.h[1] = (__bf16)h2[1];
            pku = pk.u;
            // hot-window agent store (the ONLY store on the drain path)
            unsigned* hw = (unsigned*)(hbuf + (size_t)((t + 1) & 1) * (BATCH * HID)
                                       + (size_t)b2 * HID + jb + up0);
            __hip_atomic_store(hw, pku, __ATOMIC_RELAXED, __HIP_MEMORY_SCOPE_AGENT);
        }

        if (t + 1 == TSTEP){
            if (tid < 256)      // last step: Hall store, flushed at kernel end
                *(unsigned*)(Hall + ((size_t)t * BATCH + b2) * HID + jb + up0) = pku;
            break;
        }

        // ---- device barrier: drain hbuf store, flag, deferred Hall, poll ----
        __syncthreads();                 // vmcnt(0): hbuf agent store COMPLETE
        if (tid == 0)
            __hip_atomic_store(&flags[blockIdx.x * FSTRIDE], (unsigned)(t + 1),
                               __ATOMIC_RELAXED, __HIP_MEMORY_SCOPE_AGENT);
        if (tid < 256)                   // Hall store OFF the drain path
            *(unsigned*)(Hall + ((size_t)t * BATCH + b2) * HID + jb + up0) = pku;
        if (wid == 0){
            const unsigned tgt = (unsigned)(t + 1);
            for (;;){
                unsigned f0 = __hip_atomic_load(&flags[lane * FSTRIDE],
                                  __ATOMIC_RELAXED, __HIP_MEMORY_SCOPE_AGENT);
                if (f0 >= tgt) break;
                __builtin_amdgcn_s_sleep(1);
            }
        }
        __syncthreads();
    }
}

// ---------------------------------------------------------------------------
extern "C" void kernel_launch(void* const* d_in, const int* in_sizes, int n_in,
                              void* d_out, int out_size, void* d_ws, size_t ws_size,
                              hipStream_t stream)
{
    const float* latent = (const float*)d_in[0];
    const int*   tokens = (const int*)d_in[1];
    const float* emb    = (const float*)d_in[2];
    const float* Wlh    = (const float*)d_in[3];
    const float* blh    = (const float*)d_in[4];
    const float* Wih    = (const float*)d_in[5];
    const float* bih    = (const float*)d_in[6];
    const float* Whh    = (const float*)d_in[7];
    const float* bhh    = (const float*)d_in[8];
    const float* Wout   = (const float*)d_in[9];
    const float* bout   = (const float*)d_in[10];
    float* out = (float*)d_out;

    const size_t xg_b   = (size_t)MPAD * G4 * 4;        // 64 MiB fp32 gate preacts
    const size_t hall_b = (size_t)MPAD * HID * 2;       // 8 MiB bf16
    const size_t whh_b  = (size_t)G4 * HID * 2;         // 8 MiB bf16
    const size_t wout_b = (size_t)VOCAB * HID * 2;      // 62.5 MiB bf16
    const size_t hb_b   = (size_t)2 * BATCH * HID * 2;  // 128 KiB ping-pong
    const size_t cnt_b  = (size_t)128 * FSTRIDE * 4;    // 32 KiB scattered flags

    char* p = (char*)d_ws;
    const bool wsA = ws_size >= xg_b + hall_b + whh_b + wout_b + hb_b + cnt_b;
    const bool wsB = ws_size >= hall_b + whh_b + wout_b + hb_b + cnt_b;

    float* xg;
    if (wsA){ xg = (float*)p; p += xg_b; }
    else    { xg = (float*)d_out; }      // 64 MiB scratch; consumed before K3 writes
    __bf16* Hall = (__bf16*)p; p += hall_b;
    __bf16* Whhb = (__bf16*)p; p += whh_b;
    __bf16* Woutb = nullptr;
    if (wsA || wsB){ Woutb = (__bf16*)p; p += wout_b; }
    __bf16* hbuf = (__bf16*)p; p += hb_b;
    unsigned* flags = (unsigned*)p; p += cnt_b;

    init_kernel<<<dim3(192), dim3(256), 0, stream>>>(
        latent, Wlh, blh, hbuf, Hall, flags, Whh, Whhb);

    gemm_xg<<<dim3(G4 / 128, MPAD / 128), dim3(256), 0, stream>>>(
        emb, Wih, tokens, xg, bih, bhh);

    {
        const float*  xgc   = xg;
        __bf16*       hallp = Hall;
        __bf16*       hbp   = hbuf;
        const __bf16* whhp  = Whhb;
        unsigned*     flagp = flags;
        const float*  wof   = Wout;
        __bf16*       wob   = Woutb;
        void* args[] = { (void*)&xgc, (void*)&hallp, (void*)&hbp, (void*)&whhp,
                         (void*)&flagp, (void*)&wof, (void*)&wob };
        (void)hipLaunchCooperativeKernel((void*)lstm_coop, dim3(256), dim3(512),
                                         args, 0, stream);
    }

    if (Woutb)
        gemm_logits<1><<<dim3(NTM * NTN), dim3(256), 0, stream>>>(
            Hall, (const float*)nullptr, Woutb, out, bout);
    else
        gemm_logits<0><<<dim3(NTM * NTN), dim3(256), 0, stream>>>(
            Hall, Wout, (const __bf16*)nullptr, out, bout);
}

// Round 18
// 1184.555 us; speedup vs baseline: 1.3494x; 1.0217x over previous
//
#include <hip/hip_runtime.h>
#include <cstdint>

typedef __bf16 bf16x8 __attribute__((ext_vector_type(8)));
typedef __bf16 bf16x4 __attribute__((ext_vector_type(4)));
typedef float  f32x4  __attribute__((ext_vector_type(4)));

#define VOCAB 32000
#define EMB   512
#define HID   1024
#define LAT   512
#define BATCH 32
#define TSTEP 127          // T-1
#define MROWS 4064         // TSTEP*BATCH
#define MPAD  4096
#define G4    4096         // 4*HID
#define NBLK2 64           // lstm worker blocks (512 thr each)
#define NTM   32           // logits M tiles
#define NTN   250          // logits N tiles
#define FSTRIDE 64         // flag spacing in u32 (256 B apart, line-exclusive)

__device__ __forceinline__ float sigf(float x){ return 1.0f / (1.0f + __expf(-x)); }
__device__ __forceinline__ float tanhfast(float x){
    float ax = fabsf(x);
    float e  = __expf(-2.0f * ax);
    float t  = (1.0f - e) / (1.0f + e);
    return copysignf(t, x);
}

// async global->LDS, 16B/lane; LDS base wave-uniform (HW adds lane*16)
__device__ __forceinline__ void gll16(void* lds, const void* gsrc){
    __builtin_amdgcn_global_load_lds(
        (const __attribute__((address_space(1))) unsigned int*)gsrc,
        (__attribute__((address_space(3))) unsigned int*)lds,
        16, 0, 0);
}

// ---------------------------------------------------------------------------
// K0 (grid 192): blocks 0..127: h0 = latent@W_lh^T + b_lh -> hbuf[0]; zero
// Hall pad rows; zero scattered flags. blocks 128..191: W_hh fp32->bf16.
// ---------------------------------------------------------------------------
__global__ __launch_bounds__(256) void init_kernel(
    const float* __restrict__ latent,
    const float* __restrict__ Wlh,
    const float* __restrict__ blh,
    __bf16* __restrict__ h0,
    __bf16* __restrict__ Hall,
    unsigned* __restrict__ flags,
    const float* __restrict__ Whh,
    __bf16* __restrict__ Whhb)
{
    if (blockIdx.x >= 128){
        const int n4 = G4 * HID / 4;
        for (int i = (blockIdx.x - 128) * 256 + threadIdx.x; i < n4; i += 64 * 256){
            float4 v = ((const float4*)Whh)[i];
            bf16x4 o = { (__bf16)v.x, (__bf16)v.y, (__bf16)v.z, (__bf16)v.w };
            ((bf16x4*)Whhb)[i] = o;
        }
        return;
    }
    if (blockIdx.x == 0 && threadIdx.x < 128)
        flags[threadIdx.x * FSTRIDE] = 0u;     // one flag per 256B line

    int id = blockIdx.x * 256 + threadIdx.x;   // 32768 = BATCH*HID
    int b = id >> 10, j = id & 1023;
    float s = blh[j];
    const float4* lr = (const float4*)(latent + (size_t)b * LAT);
    const float4* wr = (const float4*)(Wlh + (size_t)j * LAT);
    for (int k = 0; k < LAT / 4; ++k){
        float4 a = lr[k], w = wr[k];
        s += a.x * w.x + a.y * w.y + a.z * w.z + a.w * w.w;
    }
    h0[id] = (__bf16)s;                         // hbuf[0][b][j]
    Hall[(size_t)MROWS * HID + id] = (__bf16)0.0f;  // pad rows 4064..4095
}

// ---------------------------------------------------------------------------
// K1: xg[r][4096] = emb[tok(r)] @ W_ih^T + b_ih + b_hh   (fp32 in, fp32 out)
// ---------------------------------------------------------------------------
__global__ __launch_bounds__(256) void gemm_xg(
    const float* __restrict__ emb,
    const float* __restrict__ Wih,
    const int*   __restrict__ tok,
    float*       __restrict__ xg,
    const float* __restrict__ bih,
    const float* __restrict__ bhh)
{
    __shared__ __bf16 As[2][128 * 32];
    __shared__ __bf16 Bs[2][128 * 32];

    const int tid  = threadIdx.x;
    const int wid  = tid >> 6, lane = tid & 63;
    const int tile_n = blockIdx.x, tile_m = blockIdx.y;
    const int wr = wid >> 1, wc = wid & 1;

    f32x4 acc[4][4] = {};

    auto stage = [&](int kt, int buf){
        #pragma unroll
        for (int j = 0; j < 2; ++j){
            const int slot = tid + j * 256;
            const int row  = slot >> 2;
            const int kb   = kt * 32 + (slot & 3) * 8;
            {
                const int brow = tile_n * 128 + row;
                const float4* p = (const float4*)(Wih + (size_t)brow * EMB + kb);
                float4 u = p[0], v = p[1];
                bf16x8 w = { (__bf16)u.x, (__bf16)u.y, (__bf16)u.z, (__bf16)u.w,
                             (__bf16)v.x, (__bf16)v.y, (__bf16)v.z, (__bf16)v.w };
                *(bf16x8*)&Bs[buf][row * 32 + (slot & 3) * 8] = w;
            }
            {
                int r = tile_m * 128 + row;
                int rc = (r < MROWS) ? r : (MROWS - 1);
                int token = tok[(rc & 31) * 128 + (rc >> 5)];   // tokens[b][t]
                const float4* p = (const float4*)(emb + (size_t)token * EMB + kb);
                float4 u = p[0], v = p[1];
                bf16x8 w = { (__bf16)u.x, (__bf16)u.y, (__bf16)u.z, (__bf16)u.w,
                             (__bf16)v.x, (__bf16)v.y, (__bf16)v.z, (__bf16)v.w };
                *(bf16x8*)&As[buf][row * 32 + (slot & 3) * 8] = w;
            }
        }
    };

    const int KT = EMB / 32;
    stage(0, 0);
    for (int kt = 0; kt < KT; ++kt){
        const int buf = kt & 1;
        __syncthreads();
        if (kt + 1 < KT) stage(kt + 1, buf ^ 1);
        const __bf16* Abuf = As[buf];
        const __bf16* Bbuf = Bs[buf];
        const int ar = lane & 15, ko = (lane >> 4) * 8;
        bf16x8 av[4], bv[4];
        #pragma unroll
        for (int m = 0; m < 4; ++m)
            av[m] = *(const bf16x8*)&Abuf[(wr * 64 + m * 16 + ar) * 32 + ko];
        #pragma unroll
        for (int n = 0; n < 4; ++n)
            bv[n] = *(const bf16x8*)&Bbuf[(wc * 64 + n * 16 + ar) * 32 + ko];
        #pragma unroll
        for (int m = 0; m < 4; ++m)
            #pragma unroll
            for (int n = 0; n < 4; ++n)
                acc[m][n] = __builtin_amdgcn_mfma_f32_16x16x32_bf16(av[m], bv[n], acc[m][n], 0, 0, 0);
    }

    const int r0 = tile_m * 128 + wr * 64 + ((lane >> 4) << 2);
    const int c0 = tile_n * 128 + wc * 64 + (lane & 15);
    #pragma unroll
    for (int m = 0; m < 4; ++m){
        #pragma unroll
        for (int n = 0; n < 4; ++n){
            const int col = c0 + n * 16;
            float badd = bih[col] + bhh[col];
            #pragma unroll
            for (int q = 0; q < 4; ++q){
                int row = r0 + m * 16 + q;
                xg[(size_t)row * G4 + col] = acc[m][n][q] + badd;
            }
        }
    }
}

// ---------------------------------------------------------------------------
// K3: logits = Hall @ W_out^T + b_out, 128^2 tile, GROUP_M=8 + XCD swizzle.
// Swapped MFMA operands -> lane holds 4 consecutive output cols -> f32x4
// nontemporal C-stores.
// ---------------------------------------------------------------------------
template<int BF16B>
__global__ __launch_bounds__(256) void gemm_logits(
    const __bf16* __restrict__ A,     // Hall, padded to MPAD rows, K=HID
    const float*  __restrict__ Bf,    // W_out fp32 (BF16B=0)
    const __bf16* __restrict__ Bb,    // W_out bf16 (BF16B=1)
    float*        __restrict__ C,
    const float*  __restrict__ bias)
{
    __shared__ __bf16 As[2][128 * 32];
    __shared__ __bf16 Bs[2][128 * 32];

    const int tid  = threadIdx.x;
    const int wid  = tid >> 6, lane = tid & 63;
    const int bid = blockIdx.x;
    const int s   = (bid & 7) * (NTM * NTN / 8) + (bid >> 3);
    const int g   = s / (8 * NTN), rem = s % (8 * NTN);
    const int tile_m = g * 8 + (rem & 7);
    const int tile_n = rem >> 3;
    const int wr = wid >> 1, wc = wid & 1;

    f32x4 acc[4][4] = {};

    auto stage = [&](int kt, int buf){
        const int kb = kt * 32 + (lane & 3) * 8;
        #pragma unroll
        for (int c2 = 0; c2 < 2; ++c2){
            int rA = tile_m * 128 + c2 * 64 + wid * 16 + (lane >> 2);
            gll16(&As[buf][c2 * 2048 + wid * 512], A + (size_t)rA * HID + kb);
            if constexpr (BF16B){
                int rB = tile_n * 128 + c2 * 64 + wid * 16 + (lane >> 2);
                gll16(&Bs[buf][c2 * 2048 + wid * 512], Bb + (size_t)rB * HID + kb);
            }
        }
        if constexpr (!BF16B){
            #pragma unroll
            for (int j = 0; j < 2; ++j){
                const int slot = tid + j * 256;
                const int row  = slot >> 2;
                const int kb2  = kt * 32 + (slot & 3) * 8;
                const int brow = tile_n * 128 + row;
                const float4* p = (const float4*)(Bf + (size_t)brow * HID + kb2);
                float4 u = p[0], v = p[1];
                bf16x8 w = { (__bf16)u.x, (__bf16)u.y, (__bf16)u.z, (__bf16)u.w,
                             (__bf16)v.x, (__bf16)v.y, (__bf16)v.z, (__bf16)v.w };
                *(bf16x8*)&Bs[buf][row * 32 + (slot & 3) * 8] = w;
            }
        }
    };

    const int KT = HID / 32;
    stage(0, 0);
    for (int kt = 0; kt < KT; ++kt){
        const int buf = kt & 1;
        __syncthreads();                 // drains vmcnt (gll) + lgkmcnt
        if (kt + 1 < KT) stage(kt + 1, buf ^ 1);
        const __bf16* Abuf = As[buf];
        const __bf16* Bbuf = Bs[buf];
        const int ar = lane & 15, ko = (lane >> 4) * 8;
        bf16x8 av[4], bv[4];
        #pragma unroll
        for (int m = 0; m < 4; ++m)
            av[m] = *(const bf16x8*)&Abuf[(wr * 64 + m * 16 + ar) * 32 + ko];
        #pragma unroll
        for (int n = 0; n < 4; ++n)
            bv[n] = *(const bf16x8*)&Bbuf[(wc * 64 + n * 16 + ar) * 32 + ko];
        #pragma unroll
        for (int m = 0; m < 4; ++m)
            #pragma unroll
            for (int n = 0; n < 4; ++n)
                acc[m][n] = __builtin_amdgcn_mfma_f32_16x16x32_bf16(
                    bv[n], av[m], acc[m][n], 0, 0, 0);   // SWAPPED
    }

    const int r0 = tile_m * 128 + wr * 64 + (lane & 15);
    const int c0 = tile_n * 128 + wc * 64 + ((lane >> 4) << 2);
    #pragma unroll
    for (int m = 0; m < 4; ++m){
        const int row = r0 + m * 16;
        if (row < MROWS){
            const int t = row >> 5, b = row & 31;
            float* crow = &C[((size_t)b * TSTEP + t) * VOCAB];
            #pragma unroll
            for (int n = 0; n < 4; ++n){
                const int col = c0 + n * 16;
                const f32x4 bd = *(const f32x4*)&bias[col];
                f32x4 v = acc[m][n] + bd;
                __builtin_nontemporal_store(v, (f32x4*)&crow[col]);
            }
        }
    }
}

// ---------------------------------------------------------------------------
// K2: 127 LSTM steps, ONE cooperative kernel (256 blocks x 512 thr):
//   blocks 0..63   : LSTM, 16 units each, 8-wave K-split. PRODUCER-SUBSET
//                    wait: wave w consumes h-units [128w,128w+128) written
//                    by blocks [8w,8w+8) only -> each wave polls just its 8
//                    producer flags and starts loads/MFMA immediately (no
//                    global barrier poll). Depth-2 hbuf stays safe: a block
//                    flags t+1 only after ALL its waves read h_t, and
//                    entering step t+1 transitively requires all 64 blocks
//                    at flag>=t+1.
//   blocks 64..255 : W_out fp32->bf16 under the lstm shadow, then exit.
// ---------------------------------------------------------------------------
__global__ __launch_bounds__(512) void lstm_coop(
    const float*  __restrict__ xg,
    __bf16*       __restrict__ Hall,
    __bf16*       __restrict__ hbuf,    // 2 * BATCH*HID ping-pong, [0]=h0
    const __bf16* __restrict__ Whhb,
    unsigned*     __restrict__ flags,   // 64 flags, 256B apart
    const float*  __restrict__ Woutf,
    __bf16*       __restrict__ Woutb)
{
    if (blockIdx.x >= NBLK2){
        if (Woutb){
            const int n4 = VOCAB * HID / 4;          // 8.192M float4
            for (int i = (blockIdx.x - NBLK2) * 512 + threadIdx.x; i < n4; i += 192 * 512){
                float4 v = ((const float4*)Woutf)[i];
                bf16x4 o = { (__bf16)v.x, (__bf16)v.y, (__bf16)v.z, (__bf16)v.w };
                ((bf16x4*)Woutb)[i] = o;
            }
        }
        return;
    }

    __shared__ float lds_g[8 * 8 * 4 * 64];    // [bh*4+cf][wave][q][lane] = 64KB
    const int tid = threadIdx.x, wid = tid >> 6, lane = tid & 63;
    const int jb = blockIdx.x * 16;            // 16 units per block

    // B-frags: 4 col-fragments (= gate types) x 4 ks; this wave's K-eighth.
    bf16x8 bfrag[4][4];
    {
        const int un = lane & 15, ko = (lane >> 4) * 8;
        #pragma unroll
        for (int cf = 0; cf < 4; ++cf){
            const __bf16* base =
                Whhb + ((size_t)cf * HID + jb + un) * HID + wid * 128 + ko;
            #pragma unroll
            for (int ks = 0; ks < 4; ++ks)
                bfrag[cf][ks] = *(const bf16x8*)(base + ks * 32);
        }
    }

    // update-phase ownership: tid<256, (batch b2, 2 units up0..up0+1)
    const int b2 = tid >> 3, up0 = (tid & 7) * 2;
    const int mt2 = b2 >> 4, r2 = b2 & 15, reg2 = r2 & 3, lb2 = (r2 >> 2) << 4;
    float cst[2] = {0.0f, 0.0f};

    const float* xq = xg + (size_t)b2 * G4 + jb + up0;
    float2 xv[4];
    if (tid < 256){
        #pragma unroll
        for (int g = 0; g < 4; ++g) xv[g] = *(const float2*)(xq + g * HID);
    }

    const size_t e0 = (size_t)(lane & 15) * HID + wid * 128 + (lane >> 4) * 8; // elems
    const int pflag = (wid * 8 + (lane & 7)) * FSTRIDE;   // this wave's producers

    for (int t = 0; t < TSTEP; ++t){
        // ---- per-wave producer wait: need flag >= t (h_t slice visible) ----
        if (t > 0){
            const unsigned tgt = (unsigned)t;
            for (;;){
                unsigned f = __hip_atomic_load(&flags[pflag],
                                __ATOMIC_RELAXED, __HIP_MEMORY_SCOPE_AGENT);
                if (f >= tgt) break;
                __builtin_amdgcn_s_sleep(1);
            }
        }

        // ---- batched h loads: this wave's K-eighth, both batch halves ----
        const unsigned long long* hq =
            (const unsigned long long*)(hbuf + (size_t)(t & 1) * (BATCH * HID));
        union { unsigned long long q[2]; bf16x8 v; } xa[8];
        #pragma unroll
        for (int ks = 0; ks < 4; ++ks){
            size_t q0 = (e0 + (size_t)ks * 32) >> 2;
            size_t q1 = q0 + ((size_t)16 * HID >> 2);
            xa[ks].q[0]     = __hip_atomic_load(hq + q0,     __ATOMIC_RELAXED, __HIP_MEMORY_SCOPE_AGENT);
            xa[ks].q[1]     = __hip_atomic_load(hq + q0 + 1, __ATOMIC_RELAXED, __HIP_MEMORY_SCOPE_AGENT);
            xa[4 + ks].q[0] = __hip_atomic_load(hq + q1,     __ATOMIC_RELAXED, __HIP_MEMORY_SCOPE_AGENT);
            xa[4 + ks].q[1] = __hip_atomic_load(hq + q1 + 1, __ATOMIC_RELAXED, __HIP_MEMORY_SCOPE_AGENT);
        }
        f32x4 a[2][4] = {};
        #pragma unroll
        for (int ks = 0; ks < 4; ++ks){
            #pragma unroll
            for (int cf = 0; cf < 4; ++cf){
                a[0][cf] = __builtin_amdgcn_mfma_f32_16x16x32_bf16(xa[ks].v,     bfrag[cf][ks], a[0][cf], 0, 0, 0);
                a[1][cf] = __builtin_amdgcn_mfma_f32_16x16x32_bf16(xa[4 + ks].v, bfrag[cf][ks], a[1][cf], 0, 0, 0);
            }
        }
        #pragma unroll
        for (int bh = 0; bh < 2; ++bh)
            #pragma unroll
            for (int cf = 0; cf < 4; ++cf)
                #pragma unroll
                for (int q = 0; q < 4; ++q)
                    lds_g[((((bh * 4 + cf) * 8 + wid) * 4) + q) * 64 + lane] = a[bh][cf][q];
        __syncthreads();

        // ---- update phase: 256 threads, 2 units each ----
        unsigned pku = 0;
        if (tid < 256){
            const float* xn = xq + (size_t)(t + 1) * (BATCH * G4);
            float2 xnew[4];
            #pragma unroll
            for (int g = 0; g < 4; ++g) xnew[g] = *(const float2*)(xn + g * HID);

            float h2[2];
            #pragma unroll
            for (int du = 0; du < 2; ++du){
                int u2 = up0 + du;                 // unit in [0,16)
                float gate[4];
                #pragma unroll
                for (int ty = 0; ty < 4; ++ty){
                    int li = lb2 | u2;
                    float s = 0.0f;
                    #pragma unroll
                    for (int w = 0; w < 8; ++w)
                        s += lds_g[((((mt2 * 4 + ty) * 8 + w) * 4) + reg2) * 64 + li];
                    gate[ty] = s;
                }
                float gi = gate[0] + ((du == 0) ? xv[0].x : xv[0].y);
                float gf = gate[1] + ((du == 0) ? xv[1].x : xv[1].y);
                float gc = gate[2] + ((du == 0) ? xv[2].x : xv[2].y);
                float go = gate[3] + ((du == 0) ? xv[3].x : xv[3].y);
                float c = sigf(gf) * cst[du] + sigf(gi) * tanhfast(gc);
                cst[du] = c;
                h2[du] = sigf(go) * tanhfast(c);
            }
            #pragma unroll
            for (int g = 0; g < 4; ++g) xv[g] = xnew[g];

            union { __bf16 h[2]; unsigned u; } pk;
            pk.h[0] = (__bf16)h2[0]; pk.h[1] = (__bf16)h2[1];
            pku = pk.u;
            // hot-window agent store (the ONLY store on the drain path)
            unsigned* hw = (unsigned*)(hbuf + (size_t)((t + 1) & 1) * (BATCH * HID)
                                       + (size_t)b2 * HID + jb + up0);
            __hip_atomic_store(hw, pku, __ATOMIC_RELAXED, __HIP_MEMORY_SCOPE_AGENT);
        }

        if (t + 1 == TSTEP){
            if (tid < 256)      // last step: Hall store, flushed at kernel end
                *(unsigned*)(Hall + ((size_t)t * BATCH + b2) * HID + jb + up0) = pku;
            break;
        }

        // ---- publish: drain h stores, then single flag store; NO global poll
        __syncthreads();                 // vmcnt(0): hbuf agent stores COMPLETE
        if (tid == 0)
            __hip_atomic_store(&flags[blockIdx.x * FSTRIDE], (unsigned)(t + 1),
                               __ATOMIC_RELAXED, __HIP_MEMORY_SCOPE_AGENT);
        if (tid < 256)                   // Hall store off the critical path
            *(unsigned*)(Hall + ((size_t)t * BATCH + b2) * HID + jb + up0) = pku;
        // next iteration's per-wave producer poll replaces the global barrier;
        // lds_g reuse is safe: writes happen after that poll + loads + MFMA,
        // and all update-phase reads completed before the drain barrier above.
    }
}

// ---------------------------------------------------------------------------
extern "C" void kernel_launch(void* const* d_in, const int* in_sizes, int n_in,
                              void* d_out, int out_size, void* d_ws, size_t ws_size,
                              hipStream_t stream)
{
    const float* latent = (const float*)d_in[0];
    const int*   tokens = (const int*)d_in[1];
    const float* emb    = (const float*)d_in[2];
    const float* Wlh    = (const float*)d_in[3];
    const float* blh    = (const float*)d_in[4];
    const float* Wih    = (const float*)d_in[5];
    const float* bih    = (const float*)d_in[6];
    const float* Whh    = (const float*)d_in[7];
    const float* bhh    = (const float*)d_in[8];
    const float* Wout   = (const float*)d_in[9];
    const float* bout   = (const float*)d_in[10];
    float* out = (float*)d_out;

    const size_t xg_b   = (size_t)MPAD * G4 * 4;        // 64 MiB fp32 gate preacts
    const size_t hall_b = (size_t)MPAD * HID * 2;       // 8 MiB bf16
    const size_t whh_b  = (size_t)G4 * HID * 2;         // 8 MiB bf16
    const size_t wout_b = (size_t)VOCAB * HID * 2;      // 62.5 MiB bf16
    const size_t hb_b   = (size_t)2 * BATCH * HID * 2;  // 128 KiB ping-pong
    const size_t cnt_b  = (size_t)128 * FSTRIDE * 4;    // 32 KiB scattered flags

    char* p = (char*)d_ws;
    const bool wsA = ws_size >= xg_b + hall_b + whh_b + wout_b + hb_b + cnt_b;
    const bool wsB = ws_size >= hall_b + whh_b + wout_b + hb_b + cnt_b;

    float* xg;
    if (wsA){ xg = (float*)p; p += xg_b; }
    else    { xg = (float*)d_out; }      // 64 MiB scratch; consumed before K3 writes
    __bf16* Hall = (__bf16*)p; p += hall_b;
    __bf16* Whhb = (__bf16*)p; p += whh_b;
    __bf16* Woutb = nullptr;
    if (wsA || wsB){ Woutb = (__bf16*)p; p += wout_b; }
    __bf16* hbuf = (__bf16*)p; p += hb_b;
    unsigned* flags = (unsigned*)p; p += cnt_b;

    init_kernel<<<dim3(192), dim3(256), 0, stream>>>(
        latent, Wlh, blh, hbuf, Hall, flags, Whh, Whhb);

    gemm_xg<<<dim3(G4 / 128, MPAD / 128), dim3(256), 0, stream>>>(
        emb, Wih, tokens, xg, bih, bhh);

    {
        const float*  xgc   = xg;
        __bf16*       hallp = Hall;
        __bf16*       hbp   = hbuf;
        const __bf16* whhp  = Whhb;
        unsigned*     flagp = flags;
        const float*  wof   = Wout;
        __bf16*       wob   = Woutb;
        void* args[] = { (void*)&xgc, (void*)&hallp, (void*)&hbp, (void*)&whhp,
                         (void*)&flagp, (void*)&wof, (void*)&wob };
        (void)hipLaunchCooperativeKernel((void*)lstm_coop, dim3(256), dim3(512),
                                         args, 0, stream);
    }

    if (Woutb)
        gemm_logits<1><<<dim3(NTM * NTN), dim3(256), 0, stream>>>(
            Hall, (const float*)nullptr, Woutb, out, bout);
    else
        gemm_logits<0><<<dim3(NTM * NTN), dim3(256), 0, stream>>>(
            Hall, Wout, (const __bf16*)nullptr, out, bout);
}